// Round 15
// baseline (100.457 us; speedup 1.0000x reference)
//
#include <hip/hip_runtime.h>
#include <hip/hip_bf16.h>

typedef unsigned short u16;
typedef unsigned int u32;
typedef short bf16x8 __attribute__((ext_vector_type(8)));
typedef float f32x4 __attribute__((ext_vector_type(4)));
typedef u32 u32x4 __attribute__((ext_vector_type(4)));

#define N_TOK 4096
#define C_DIM 256
#define HEADS 8
#define HD 32
#define SCALE_F 0.17677669529663687f   /* 32^-0.5 */

__device__ inline u16 f2bf(float f) {
    u32 u = __float_as_uint(f);
    u += 0x7fffu + ((u >> 16) & 1u);
    return (u16)(u >> 16);
}
__device__ inline float b2f(u16 h) { return __uint_as_float((u32)h << 16); }
__device__ inline float bf_lo(u32 u) { return __uint_as_float(u << 16); }
__device__ inline float bf_hi(u32 u) { return __uint_as_float(u & 0xffff0000u); }

__device__ inline void gload16(const void* g, void* l) {
    __builtin_amdgcn_global_load_lds((const __attribute__((address_space(1))) u32*)g,
                                     (__attribute__((address_space(3))) u32*)l, 16, 0, 0);
}

// ---------------- stage1: transpose_x 64x64 tiles (0..2047) + weight prep (2048..3071) + sc (3072..3135) ----------------
__global__ __launch_bounds__(256) void stage1(const float* __restrict__ x, const float* __restrict__ w1,
                                              const float* __restrict__ w2, const float* __restrict__ s,
                                              const float* __restrict__ c, u16* __restrict__ xT,
                                              u16* __restrict__ o1, u16* __restrict__ o2, u32* __restrict__ scT) {
    __shared__ char smem[16896];
    int bx = blockIdx.x;
    int t = threadIdx.x;
    if (bx < 2048) {
        int lt = bx & 63, ct = (bx >> 6) & 3, b = bx >> 8;
        int l0 = lt * 64, c0 = ct * 64;
        const float* xb = x + ((size_t)b * C_DIM + c0) * N_TOK + l0;
        float* tl = (float*)smem;      // [64 l][65]
#pragma unroll
        for (int i = 0; i < 4; ++i) {
            int id = i * 256 + t;
            int ci = id >> 4, lj = id & 15;
            f32x4 v = *(const f32x4*)(xb + (size_t)ci * N_TOK + lj * 4);
#pragma unroll
            for (int e = 0; e < 4; ++e) tl[(lj * 4 + e) * 65 + ci] = v[e];
        }
        __syncthreads();
#pragma unroll
        for (int j = 0; j < 2; ++j) {
            int id = j * 256 + t;
            int l = id >> 3, cg = id & 7;
            u16 o[8];
#pragma unroll
            for (int e = 0; e < 8; ++e) o[e] = f2bf(tl[l * 65 + cg * 8 + e]);
            uint4 u;
            u.x = (u32)o[0] | ((u32)o[1] << 16);
            u.y = (u32)o[2] | ((u32)o[3] << 16);
            u.z = (u32)o[4] | ((u32)o[5] << 16);
            u.w = (u32)o[6] | ((u32)o[7] << 16);
            *(uint4*)(xT + ((size_t)b * N_TOK + l0 + l) * C_DIM + c0 + cg * 8) = u;
        }
        return;
    }
    int px = bx - 2048;
    if (px < 1024) {
        int i = px * 256 + t;
        o1[i] = f2bf(w1[i]);
        if (i < 256 * 256) o2[i] = f2bf(w2[i]);
        return;
    }
    int l0 = (px - 1024) * 64;
    float (*ts)[33] = (float(*)[33])smem;
    float (*tc)[33] = (float(*)[33])(smem + 8448);
    int d = t & 31, r = t >> 5;
#pragma unroll
    for (int i = 0; i < 8; ++i) {
        ts[r + i * 8][d] = s[(size_t)(l0 + r + i * 8) * HD + d];
        tc[r + i * 8][d] = c[(size_t)(l0 + r + i * 8) * HD + d];
    }
    __syncthreads();
    int li = t & 63, dr = t >> 6;
#pragma unroll
    for (int i = 0; i < 8; ++i) {
        int dd = dr * 8 + i;
        scT[(size_t)dd * N_TOK + l0 + li] = (u32)f2bf(ts[li][dd]) | ((u32)f2bf(tc[li][dd]) << 16);
    }
}

// ---------------- proj GEMM (fp32 out): 128x128 tile, BK=64, XOR slot swizzle ----------------
__global__ __launch_bounds__(256) void gemm_proj(const u16* __restrict__ A, const u16* __restrict__ Bm,
                                                 const float* __restrict__ bias, float* __restrict__ C,
                                                 int M, int L, int K) {
    int bt = blockIdx.z;
    int m0 = blockIdx.y * 128;
    int l0 = blockIdx.x * 128;
    const u16* Bb = Bm + (size_t)bt * L * K;
    float* Cb = C + (size_t)bt * M * L;

    __shared__ u16 smem[17408];
    u16* As = smem;
    u16* Bs = smem + 8192;

    int t = threadIdx.x;
    int w = t >> 6, lane = t & 63;
    int wr = (w >> 1) * 64, wc = (w & 1) * 64;
    int fr = lane & 15, kg = lane >> 4;

    f32x4 acc[4][4] = {};

    for (int k0 = 0; k0 < K; k0 += 64) {
#pragma unroll
        for (int j = 0; j < 4; ++j) {
            int c = j * 256 + w * 64 + lane;
            int row = c >> 3, slot = c & 7;
            int gslot = slot ^ (row & 7);
            u16* abase = As + (size_t)(j * 256 + w * 64) * 8;
            u16* bbase = Bs + (size_t)(j * 256 + w * 64) * 8;
            gload16(A + (size_t)(m0 + row) * K + k0 + gslot * 8, abase);
            gload16(Bb + (size_t)(l0 + row) * K + k0 + gslot * 8, bbase);
        }
        __syncthreads();
#pragma unroll
        for (int kk = 0; kk < 2; ++kk) {
            bf16x8 af[4], bfr[4];
#pragma unroll
            for (int i = 0; i < 4; ++i) {
                int ra = wr + i * 16 + fr;
                int rb = wc + i * 16 + fr;
                af[i]  = *(const bf16x8*)(As + (size_t)ra * 64 + (size_t)((kk * 4 + kg) ^ (ra & 7)) * 8);
                bfr[i] = *(const bf16x8*)(Bs + (size_t)rb * 64 + (size_t)((kk * 4 + kg) ^ (rb & 7)) * 8);
            }
#pragma unroll
            for (int i = 0; i < 4; ++i)
#pragma unroll
                for (int jj = 0; jj < 4; ++jj)
                    acc[i][jj] = __builtin_amdgcn_mfma_f32_16x16x32_bf16(af[i], bfr[jj], acc[i][jj], 0, 0, 0);
        }
        __syncthreads();
    }

    int rg = (lane >> 4) * 4;
    float* Csf = (float*)smem;        // [64][132]
#pragma unroll
    for (int half = 0; half < 2; ++half) {
        if ((w >> 1) == half) {
#pragma unroll
            for (int i = 0; i < 4; ++i)
#pragma unroll
                for (int jj = 0; jj < 4; ++jj) {
                    int col = wc + jj * 16 + fr;
#pragma unroll
                    for (int r = 0; r < 4; ++r) {
                        int row = i * 16 + rg + r;
                        Csf[row * 132 + col] = acc[i][jj][r] + bias[m0 + half * 64 + row];
                    }
                }
        }
        __syncthreads();
#pragma unroll
        for (int j = 0; j < 8; ++j) {
            int id = j * 256 + t;
            int row = id >> 5, c4 = id & 31;
            *(f32x4*)(Cb + (size_t)(m0 + half * 64 + row) * L + l0 + c4 * 4) =
                *(const f32x4*)(Csf + row * 132 + c4 * 4);
        }
        __syncthreads();
    }
}

// ---------------- stage2_kv: fused k/v GEMM + elu/theta + kv outer product; per (chunk, bn) ----------------
__global__ __launch_bounds__(256) void stage2_kv(const u16* __restrict__ wbf, const float* __restrict__ bq,
                                                 const u16* __restrict__ xT, const u32* __restrict__ scT,
                                                 u16* __restrict__ v_glob, float* __restrict__ part_kv,
                                                 float* __restrict__ part_ks, float* __restrict__ part_vs) {
    int chunk = blockIdx.x & 15, bn = blockIdx.x >> 4;
    int b = bn >> 3, n = bn & 7;
    int T0 = chunk * 256;
    const u16* Bx = xT + ((size_t)b * N_TOK + T0) * C_DIM;

    __shared__ char smem[51200];
    u16* Bst = (u16*)smem;                            // [256][64] = 32768
    u16* Ast = (u16*)(smem + 32768);                  // [64][64] = 8192
    u16 (*ks_bf)[264] = (u16(*)[264])smem;            // 16896
    u16 (*v_bf)[264]  = (u16(*)[264])(smem + 16896);  // -> 33792
    float* red  = (float*)(smem + 33792);             // 16384 -> 50176
    float* redk = (float*)(smem + 50176);             // [4][32]
    float* redv = (float*)(smem + 50688);             // [4][32]

    int t = threadIdx.x;
    int w = t >> 6, lane = t & 63;
    int fr = lane & 15, kg = lane >> 4;

    float bk[8], bv[8];
#pragma unroll
    for (int i = 0; i < 2; ++i)
#pragma unroll
        for (int r = 0; r < 4; ++r) {
            bk[i * 4 + r] = bq[256 + n * HD + i * 16 + kg * 4 + r];
            bv[i * 4 + r] = bq[512 + n * HD + i * 16 + kg * 4 + r];
        }

    // ---- phase 0: GEMM 64 rows (k:0..31, v:32..63) x 256 tokens, K=256 ----
    f32x4 acc[4][4] = {};
    for (int k0 = 0; k0 < 256; k0 += 64) {
#pragma unroll
        for (int j = 0; j < 8; ++j) {
            int cc = j * 256 + w * 64 + lane;
            int row = cc >> 3, slot = cc & 7;
            int gslot = slot ^ (row & 7);
            gload16(Bx + (size_t)row * C_DIM + k0 + gslot * 8, Bst + (size_t)(j * 256 + w * 64) * 8);
        }
#pragma unroll
        for (int j = 0; j < 2; ++j) {
            int cc = j * 256 + w * 64 + lane;
            int row = cc >> 3, slot = cc & 7;
            int gslot = slot ^ (row & 7);
            int arow = (row < 32 ? 256 : 480) + n * HD + row;
            gload16(wbf + (size_t)arow * C_DIM + k0 + gslot * 8, Ast + (size_t)(j * 256 + w * 64) * 8);
        }
        __syncthreads();
#pragma unroll
        for (int kk = 0; kk < 2; ++kk) {
            bf16x8 af[4], bfr[4];
#pragma unroll
            for (int i = 0; i < 4; ++i) {
                int ra = i * 16 + fr;
                af[i] = *(const bf16x8*)(Ast + (size_t)ra * 64 + (size_t)((kk * 4 + kg) ^ (ra & 7)) * 8);
            }
#pragma unroll
            for (int jj = 0; jj < 4; ++jj) {
                int rb = w * 64 + jj * 16 + fr;
                bfr[jj] = *(const bf16x8*)(Bst + (size_t)rb * 64 + (size_t)((kk * 4 + kg) ^ (rb & 7)) * 8);
            }
#pragma unroll
            for (int i = 0; i < 4; ++i)
#pragma unroll
                for (int jj = 0; jj < 4; ++jj)
                    acc[i][jj] = __builtin_amdgcn_mfma_f32_16x16x32_bf16(af[i], bfr[jj], acc[i][jj], 0, 0, 0);
        }
        __syncthreads();
    }

    // ---- scatter: k -> elu+ksum+theta -> ks_bf; v -> vsum -> v_bf ----
    float kspart[8] = {}, vspart[8] = {};
#pragma unroll
    for (int i = 0; i < 2; ++i)
#pragma unroll
        for (int jj = 0; jj < 4; ++jj) {
            int tok = w * 64 + jj * 16 + fr;
            float k0v = acc[i][jj][0] + bk[i * 4 + 0];
            float k1v = acc[i][jj][1] + bk[i * 4 + 1];
            float k2v = acc[i][jj][2] + bk[i * 4 + 2];
            float k3v = acc[i][jj][3] + bk[i * 4 + 3];
            float e0 = k0v > 0.f ? k0v + 1.f : __expf(k0v);
            float e1 = k1v > 0.f ? k1v + 1.f : __expf(k1v);
            float e2 = k2v > 0.f ? k2v + 1.f : __expf(k2v);
            float e3 = k3v > 0.f ? k3v + 1.f : __expf(k3v);
            kspart[i * 4 + 0] += e0; kspart[i * 4 + 1] += e1;
            kspart[i * 4 + 2] += e2; kspart[i * 4 + 3] += e3;
            int d0 = i * 16 + kg * 4;
            u32 sA = scT[(size_t)(d0 + 0) * N_TOK + T0 + tok];
            u32 sB = scT[(size_t)(d0 + 1) * N_TOK + T0 + tok];
            u32 sC = scT[(size_t)(d0 + 2) * N_TOK + T0 + tok];
            u32 sD = scT[(size_t)(d0 + 3) * N_TOK + T0 + tok];
            ks_bf[d0 + 0][tok] = f2bf(e0 * bf_hi(sA) - e1 * bf_lo(sA));
            ks_bf[d0 + 1][tok] = f2bf(e1 * bf_hi(sB) + e0 * bf_lo(sB));
            ks_bf[d0 + 2][tok] = f2bf(e2 * bf_hi(sC) - e3 * bf_lo(sC));
            ks_bf[d0 + 3][tok] = f2bf(e3 * bf_hi(sD) + e2 * bf_lo(sD));
        }
#pragma unroll
    for (int i = 2; i < 4; ++i)
#pragma unroll
        for (int jj = 0; jj < 4; ++jj) {
            int tok = w * 64 + jj * 16 + fr;
#pragma unroll
            for (int r = 0; r < 4; ++r) {
                int vrow = (i - 2) * 16 + kg * 4 + r;
                float vv_ = acc[i][jj][r] + bv[(i - 2) * 4 + r];
                vspart[(i - 2) * 4 + r] += vv_;
                v_bf[vrow][tok] = f2bf(vv_);
            }
        }
#pragma unroll
    for (int m = 1; m < 16; m <<= 1) {
#pragma unroll
        for (int q = 0; q < 8; ++q) {
            kspart[q] += __shfl_xor(kspart[q], m);
            vspart[q] += __shfl_xor(vspart[q], m);
        }
    }
    if (fr == 0) {
#pragma unroll
        for (int q = 0; q < 8; ++q) {
            int row = (q >> 2) * 16 + kg * 4 + (q & 3);
            redk[w * 32 + row] = kspart[q];
            redv[w * 32 + row] = vspart[q];
        }
    }
    __syncthreads();

    // ---- MFMA outer product over 256 tokens ----
    f32x4 a2[2][2] = {};
#pragma unroll
    for (int kc = 0; kc < 2; ++kc) {
        int kcol = w * 64 + kc * 32 + kg * 8;
        bf16x8 af[2], bfv[2];
#pragma unroll
        for (int i = 0; i < 2; ++i) {
            af[i]  = *(const bf16x8*)&ks_bf[i * 16 + fr][kcol];
            bfv[i] = *(const bf16x8*)&v_bf[i * 16 + fr][kcol];
        }
#pragma unroll
        for (int i = 0; i < 2; ++i)
#pragma unroll
            for (int jj = 0; jj < 2; ++jj)
                a2[i][jj] = __builtin_amdgcn_mfma_f32_16x16x32_bf16(af[i], bfv[jj], a2[i][jj], 0, 0, 0);
    }

    // ---- cooperative v -> global (for lepe) ----
    {
        int row = t >> 3, tg = t & 7;
        u16* vg = v_glob + ((size_t)(b * C_DIM + n * HD + row)) * N_TOK + T0 + tg * 32;
#pragma unroll
        for (int q = 0; q < 4; ++q)
            *(uint4*)(vg + q * 8) = *(const uint4*)&v_bf[row][tg * 32 + q * 8];
    }
    if (t < 32) {
        float s = redk[t] + redk[32 + t] + redk[64 + t] + redk[96 + t];
        float sv = redv[t] + redv[32 + t] + redv[64 + t] + redv[96 + t];
        part_ks[((size_t)bn * 16 + chunk) * 32 + t] = s;
        part_vs[((size_t)bn * 16 + chunk) * 32 + t] = sv;
    }

#pragma unroll
    for (int i = 0; i < 2; ++i)
#pragma unroll
        for (int jj = 0; jj < 2; ++jj)
#pragma unroll
            for (int r = 0; r < 4; ++r) {
                int row = i * 16 + kg * 4 + r;
                int col = jj * 16 + fr;
                red[w * 1024 + row * 32 + col] = a2[i][jj][r];
            }
    __syncthreads();
    float* pkv = part_kv + ((size_t)bn * 16 + chunk) * 1024;
#pragma unroll
    for (int i = 0; i < 4; ++i) {
        int el = i * 256 + t;
        pkv[el] = red[el] + red[1024 + el] + red[2048 + el] + red[3072 + el];
    }
}

// ---------------- kv_final (blocks 0..63) + lepe (blocks 64..2111) ----------------
__global__ __launch_bounds__(256) void kvfinal_lepe(const float* __restrict__ part_kv, const float* __restrict__ part_ks,
                                                    const float* __restrict__ part_vs, const u16* __restrict__ v_glob,
                                                    const float* __restrict__ wl, const float* __restrict__ bl,
                                                    u16* __restrict__ kvT_bf, float* __restrict__ kmean,
                                                    float* __restrict__ vmean, u16* __restrict__ lepe) {
    __shared__ float wc5[25];
    int bx = blockIdx.x;
    int t = threadIdx.x;
    if (bx < 64) {
        int bn = bx;
        const float* p = part_kv + (size_t)bn * 16 * 1024;
        const float s2c = SCALE_F / (float)N_TOK;
#pragma unroll
        for (int i = 0; i < 4; ++i) {
            int sl = t + i * 256;
            float s = 0;
#pragma unroll
            for (int c = 0; c < 16; ++c) s += p[(size_t)c * 1024 + sl];
            float val = s * s2c;
            int d = sl >> 5, e = sl & 31;
            kvT_bf[(size_t)bn * 1024 + e * 32 + d] = f2bf(val);
        }
        if (t < 32) {
            float s = 0, sv = 0;
            for (int c = 0; c < 16; ++c) {
                s  += part_ks[((size_t)bn * 16 + c) * 32 + t];
                sv += part_vs[((size_t)bn * 16 + c) * 32 + t];
            }
            kmean[bn * 32 + t] = s * (1.f / (float)N_TOK);
            vmean[bn * 32 + t] = sv * (1.f / (float)N_TOK);
        }
        return;
    }
    int i2 = bx - 64;
    int c = i2 & 255, b = i2 >> 8;
    const u16* src = v_glob + ((size_t)(b * C_DIM + c)) * N_TOK;
    u16* dst = lepe + ((size_t)b * C_DIM + c) * N_TOK;
    if (t < 25) wc5[t] = wl[c * 25 + t];
    __syncthreads();

    int h = t >> 2, w0 = (t & 3) * 16;
    float bb = bl[c];
    float o16[16];
#pragma unroll
    for (int i = 0; i < 16; ++i) o16[i] = bb;

#pragma unroll
    for (int dh = 0; dh < 5; ++dh) {
        int gr = h + dh - 2;
        bool rowok = (gr >= 0) && (gr < 64);
        const u16* rp = src + (size_t)(rowok ? gr : 0) * 64 + w0 - 8;
        bf16x8 L0 = ((const bf16x8*)rp)[0];
        bf16x8 L1 = ((const bf16x8*)rp)[1];
        bf16x8 L2 = ((const bf16x8*)rp)[2];
        bf16x8 L3 = ((const bf16x8*)rp)[3];
        float rbuf[32];
#pragma unroll
        for (int j = 0; j < 32; ++j) {
            int col = w0 - 8 + j;
            u16 raw = (u16)(j < 8 ? L0[j] : j < 16 ? L1[j - 8] : j < 24 ? L2[j - 16] : L3[j - 24]);
            bool ok = rowok && (col >= 0) && (col < 64);
            rbuf[j] = ok ? b2f(raw) : 0.f;
        }
#pragma unroll
        for (int dw = 0; dw < 5; ++dw) {
            float wv_ = wc5[dh * 5 + dw];
#pragma unroll
            for (int ow = 0; ow < 16; ++ow)
                o16[ow] += rbuf[6 + dw + ow] * wv_;
        }
    }

    uint4 u0, u1;
    u0.x = (u32)f2bf(o16[0]) | ((u32)f2bf(o16[1]) << 16);
    u0.y = (u32)f2bf(o16[2]) | ((u32)f2bf(o16[3]) << 16);
    u0.z = (u32)f2bf(o16[4]) | ((u32)f2bf(o16[5]) << 16);
    u0.w = (u32)f2bf(o16[6]) | ((u32)f2bf(o16[7]) << 16);
    u1.x = (u32)f2bf(o16[8]) | ((u32)f2bf(o16[9]) << 16);
    u1.y = (u32)f2bf(o16[10]) | ((u32)f2bf(o16[11]) << 16);
    u1.z = (u32)f2bf(o16[12]) | ((u32)f2bf(o16[13]) << 16);
    u1.w = (u32)f2bf(o16[14]) | ((u32)f2bf(o16[15]) << 16);
    *(uint4*)(dst + h * 64 + w0) = u0;
    *(uint4*)(dst + h * 64 + w0 + 8) = u1;
}

// ---------------- attention epilogue v6: fused q/o GEMM + per-lane finish; o stays in registers ----------------
__global__ __launch_bounds__(256, 3) void attn_epilogue(const u16* __restrict__ wbf, const float* __restrict__ bq,
                                                        const u16* __restrict__ xT, const u32* __restrict__ scT,
                                                        const u16* __restrict__ kvT_bf, const float* __restrict__ kmean,
                                                        const float* __restrict__ vmean, const u16* __restrict__ lepe,
                                                        u16* __restrict__ resnT) {
    int lt = blockIdx.x, bn = blockIdx.y;
    int b = bn >> 3, n = bn & 7;
    int T0 = lt * 256;
    const u16* Bx = xT + ((size_t)b * N_TOK + T0) * C_DIM;
    const u16* lp = lepe + ((size_t)b * C_DIM + n * HD) * N_TOK;

    __shared__ char smem[45824];
    // phase0 staging: Bst @0 (32768), Ast @32768 (8192)
    // compute: qA @0 [256][40] (20480), vvb @20480 [256][40] (20480),
    //          kvb @40960 [32][40] (2560), multL @43520, zL @44544, kml @45568, vml @45696
    u16* Bst = (u16*)smem;
    u16* Ast = (u16*)(smem + 32768);
    u16* qA  = (u16*)smem;
    u16* vvb = (u16*)(smem + 20480);
    u16* kvb = (u16*)(smem + 40960);
    float* multL = (float*)(smem + 43520);
    float* zL    = (float*)(smem + 44544);
    float* kml   = (float*)(smem + 45568);
    float* vml   = (float*)(smem + 45696);

    int t = threadIdx.x;
    int w = t >> 6, lane = t & 63;
    int fr = lane & 15, kg = lane >> 4;

    if (t < 128) {
        int e = t >> 2, d0 = (t & 3) * 8;
        *(uint4*)(kvb + e * 40 + d0) = *(const uint4*)(kvT_bf + (size_t)bn * 1024 + e * 32 + d0);
    }
    if (t < 32) { kml[t] = kmean[bn * 32 + t]; vml[t] = vmean[bn * 32 + t]; }

    // per-thread biases
    float bkq[8], bko[8];
#pragma unroll
    for (int i = 0; i < 2; ++i)
#pragma unroll
        for (int r = 0; r < 4; ++r) {
            bkq[i * 4 + r] = bq[n * HD + i * 16 + kg * 4 + r];
            bko[i * 4 + r] = bq[768 + n * HD + i * 16 + kg * 4 + r];
        }

    // ---- phase 0: GEMM q,o = W_qo x xT^T ----
    f32x4 acc[4][4] = {};
    for (int k0 = 0; k0 < 256; k0 += 64) {
#pragma unroll
        for (int j = 0; j < 8; ++j) {
            int cc = j * 256 + w * 64 + lane;
            int row = cc >> 3, slot = cc & 7;
            int gslot = slot ^ (row & 7);
            gload16(Bx + (size_t)row * C_DIM + k0 + gslot * 8, Bst + (size_t)(j * 256 + w * 64) * 8);
        }
#pragma unroll
        for (int j = 0; j < 2; ++j) {
            int cc = j * 256 + w * 64 + lane;
            int row = cc >> 3, slot = cc & 7;
            int gslot = slot ^ (row & 7);
            int arow = (row < 32 ? n * HD : 736 + n * HD) + row;
            gload16(wbf + (size_t)arow * C_DIM + k0 + gslot * 8, Ast + (size_t)(j * 256 + w * 64) * 8);
        }
        __syncthreads();
        __builtin_amdgcn_s_setprio(1);
#pragma unroll
        for (int kk = 0; kk < 2; ++kk) {
            bf16x8 af[4], bfr[4];
#pragma unroll
            for (int i = 0; i < 4; ++i) {
                int ra = i * 16 + fr;
                af[i] = *(const bf16x8*)(Ast + (size_t)ra * 64 + (size_t)((kk * 4 + kg) ^ (ra & 7)) * 8);
            }
#pragma unroll
            for (int jj = 0; jj < 4; ++jj) {
                int rb = w * 64 + jj * 16 + fr;
                bfr[jj] = *(const bf16x8*)(Bst + (size_t)rb * 64 + (size_t)((kk * 4 + kg) ^ (rb & 7)) * 8);
            }
#pragma unroll
            for (int i = 0; i < 4; ++i)
#pragma unroll
                for (int jj = 0; jj < 4; ++jj)
                    acc[i][jj] = __builtin_amdgcn_mfma_f32_16x16x32_bf16(af[i], bfr[jj], acc[i][jj], 0, 0, 0);
        }
        __builtin_amdgcn_s_setprio(0);
        __syncthreads();
    }

    // scatter q (uint2-packed); pack o (rows 32..63) into registers
    u32 o_pk[2][4][2];
#pragma unroll
    for (int i = 0; i < 2; ++i)
#pragma unroll
        for (int jj = 0; jj < 4; ++jj) {
            int tok = w * 64 + jj * 16 + fr;
            uint2 qp;
            qp.x = (u32)f2bf(acc[i][jj][0] + bkq[i * 4 + 0]) | ((u32)f2bf(acc[i][jj][1] + bkq[i * 4 + 1]) << 16);
            qp.y = (u32)f2bf(acc[i][jj][2] + bkq[i * 4 + 2]) | ((u32)f2bf(acc[i][jj][3] + bkq[i * 4 + 3]) << 16);
            *(uint2*)(qA + tok * 40 + i * 16 + kg * 4) = qp;
            o_pk[i][jj][0] = (u32)f2bf(acc[2 + i][jj][0] + bko[i * 4 + 0]) |
                             ((u32)f2bf(acc[2 + i][jj][1] + bko[i * 4 + 1]) << 16);
            o_pk[i][jj][1] = (u32)f2bf(acc[2 + i][jj][2] + bko[i * 4 + 2]) |
                             ((u32)f2bf(acc[2 + i][jj][3] + bko[i * 4 + 3]) << 16);
        }
    __syncthreads();

    // ---- phase 1: per-token elu / z / theta -> q' A-tile (in place); mult,z to LDS ----
    int token = T0 + t;
    float qv[32];
    float z = 0.f;
#pragma unroll
    for (int j = 0; j < 4; ++j) {
        bf16x8 q8 = *(const bf16x8*)(qA + t * 40 + j * 8);
#pragma unroll
        for (int e = 0; e < 8; ++e) {
            float x_ = b2f((u16)q8[e]);
            float e_ = x_ > 0.f ? x_ + 1.f : __expf(x_);
            qv[j * 8 + e] = e_;
            z += e_ * kml[j * 8 + e];
        }
    }
    z *= SCALE_F;
#pragma unroll
    for (int p = 0; p < 16; ++p) {
        u32 sc0 = scT[(size_t)(2 * p) * N_TOK + token];
        u32 sc1 = scT[(size_t)(2 * p + 1) * N_TOK + token];
        float se = bf_lo(sc0), ce = bf_hi(sc0);
        float so = bf_lo(sc1), co = bf_hi(sc1);
        float a = qv[2 * p], bb = qv[2 * p + 1];
        qv[2 * p]     = a * ce - bb * se;
        qv[2 * p + 1] = bb * co + a * so;
    }
    multL[t] = 1.f + 1.f / (z + 1e-6f);
    zL[t] = z;
#pragma unroll
    for (int j4 = 0; j4 < 4; ++j4) {
        uint4 u;
        u.x = (u32)f2bf(qv[8 * j4 + 0]) | ((u32)f2bf(qv[8 * j4 + 1]) << 16);
        u.y = (u32)f2bf(qv[8 * j4 + 2]) | ((u32)f2bf(qv[8 * j4 + 3]) << 16);
        u.z = (u32)f2bf(qv[8 * j4 + 4]) | ((u32)f2bf(qv[8 * j4 + 5]) << 16);
        u.w = (u32)f2bf(qv[8 * j4 + 6]) | ((u32)f2bf(qv[8 * j4 + 7]) << 16);
        *(uint4*)(qA + t * 40 + j4 * 8) = u;
    }
    __syncthreads();

    // ---- phase 2: matvec swapped (A=kv rows=e, B=q' rows=token) -> per-lane finish ----
    {
        bf16x8 akv[2], bq8[4];
#pragma unroll
        for (int i2 = 0; i2 < 2; ++i2)
            akv[i2] = *(const bf16x8*)(kvb + (i2 * 16 + fr) * 40 + kg * 8);
#pragma unroll
        for (int jj = 0; jj < 4; ++jj)
            bq8[jj] = *(const bf16x8*)(qA + (size_t)(w * 64 + jj * 16 + fr) * 40 + kg * 8);

        f32x4 zero = {0.f, 0.f, 0.f, 0.f};
#pragma unroll
        for (int i2 = 0; i2 < 2; ++i2)
#pragma unroll
            for (int jj = 0; jj < 4; ++jj) {
                f32x4 a2 = __builtin_amdgcn_mfma_f32_16x16x32_bf16(akv[i2], bq8[jj], zero, 0, 0, 0);
                int tokloc = w * 64 + jj * 16 + fr;
                float mult = multL[tokloc];
                float zz = zL[tokloc];
                u16 ovv[4];
                ovv[0] = (u16)(o_pk[i2][jj][0] & 0xffff);
                ovv[1] = (u16)(o_pk[i2][jj][0] >> 16);
                ovv[2] = (u16)(o_pk[i2][jj][1] & 0xffff);
                ovv[3] = (u16)(o_pk[i2][jj][1] >> 16);
                u16 vvout[4];
#pragma unroll
                for (int r = 0; r < 4; ++r) {
                    int e = i2 * 16 + kg * 4 + r;
                    float lx = b2f(lp[(size_t)e * N_TOK + T0 + tokloc]);
                    float vvf = (a2[r] * mult - zz * vml[e] + lx) * b2f(ovv[r]);
                    vvout[r] = f2bf(vvf);
                }
                uint2 pk;
                pk.x = (u32)vvout[0] | ((u32)vvout[1] << 16);
                pk.y = (u32)vvout[2] | ((u32)vvout[3] << 16);
                *(uint2*)(vvb + tokloc * 40 + i2 * 16 + kg * 4) = pk;
            }
    }
    __syncthreads();

    // ---- coalesced output ----
    u16* dst0 = resnT + ((size_t)b * N_TOK + token) * C_DIM + n * HD;
#pragma unroll
    for (int g = 0; g < 4; ++g)
        ((uint4*)dst0)[g] = *(const uint4*)(vvb + t * 40 + g * 8);
}

extern "C" void kernel_launch(void* const* d_in, const int* in_sizes, int n_in,
                              void* d_out, int out_size, void* d_ws, size_t ws_size,
                              hipStream_t stream) {
    const float* x      = (const float*)d_in[0];
    const float* sinp   = (const float*)d_in[1];
    const float* cosp   = (const float*)d_in[2];
    const float* w_qkvo = (const float*)d_in[3];
    const float* b_qkvo = (const float*)d_in[4];
    const float* w_lepe = (const float*)d_in[5];
    const float* b_lepe = (const float*)d_in[6];
    const float* w_proj = (const float*)d_in[7];
    const float* b_proj = (const float*)d_in[8];

    char* ws = (char*)d_ws;
    size_t off = 0;
    auto alloc = [&](size_t bytes) { size_t o = off; off = (off + bytes + 255) & ~(size_t)255; return o; };
    u16*   wbf     = (u16*)(ws + alloc((size_t)1024 * 256 * 2));
    u16*   wpbf    = (u16*)(ws + alloc((size_t)256 * 256 * 2));
    u16*   xT      = (u16*)(ws + alloc((size_t)8 * 4096 * 256 * 2));
    u16*   v_glob  = (u16*)(ws + alloc((size_t)8 * 256 * 4096 * 2));
    u16*   lepe    = (u16*)(ws + alloc((size_t)8 * 256 * 4096 * 2));
    u16*   resnT   = (u16*)(ws + alloc((size_t)8 * 4096 * 256 * 2));
    float* part_kv = (float*)(ws + alloc((size_t)64 * 16 * 1024 * 4));
    float* part_ks = (float*)(ws + alloc((size_t)64 * 16 * 32 * 4));
    float* part_vs = (float*)(ws + alloc((size_t)64 * 16 * 32 * 4));
    u16*   kvT_bf  = (u16*)(ws + alloc((size_t)64 * 1024 * 2));
    float* kmean   = (float*)(ws + alloc((size_t)64 * 32 * 4));
    float* vmean   = (float*)(ws + alloc((size_t)64 * 32 * 4));
    u32*   scT     = (u32*)(ws + alloc((size_t)32 * 4096 * 4));
    if (off > ws_size) return;  // insufficient workspace -> loud validation failure

    stage1<<<dim3(3136), dim3(256), 0, stream>>>(x, w_qkvo, w_proj, sinp, cosp, xT, wbf, wpbf, scT);
    stage2_kv<<<dim3(1024), dim3(256), 0, stream>>>(wbf, b_qkvo, xT, scT, v_glob, part_kv, part_ks, part_vs);
    kvfinal_lepe<<<dim3(2112), dim3(256), 0, stream>>>(part_kv, part_ks, part_vs, v_glob, w_lepe, b_lepe,
                                                       kvT_bf, kmean, vmean, lepe);
    attn_epilogue<<<dim3(16, 64), dim3(256), 0, stream>>>(wbf, b_qkvo, xT, scT, kvT_bf, kmean, vmean, lepe, resnT);
    gemm_proj<<<dim3(32, 2, 8), dim3(256), 0, stream>>>(wpbf, resnT, b_proj, (float*)d_out, 256, 4096, 256);
}

// Round 16
// 93.695 us; speedup vs baseline: 1.0722x; 1.0722x over previous
//
#include <hip/hip_runtime.h>
#include <hip/hip_bf16.h>

typedef unsigned short u16;
typedef unsigned int u32;
typedef short bf16x8 __attribute__((ext_vector_type(8)));
typedef float f32x4 __attribute__((ext_vector_type(4)));
typedef u32 u32x4 __attribute__((ext_vector_type(4)));

#define N_TOK 4096
#define C_DIM 256
#define HEADS 8
#define HD 32
#define SCALE_F 0.17677669529663687f   /* 32^-0.5 */

__device__ inline u16 f2bf(float f) {
    u32 u = __float_as_uint(f);
    u += 0x7fffu + ((u >> 16) & 1u);
    return (u16)(u >> 16);
}
__device__ inline float b2f(u16 h) { return __uint_as_float((u32)h << 16); }
__device__ inline float bf_lo(u32 u) { return __uint_as_float(u << 16); }
__device__ inline float bf_hi(u32 u) { return __uint_as_float(u & 0xffff0000u); }

__device__ inline void gload16(const void* g, void* l) {
    __builtin_amdgcn_global_load_lds((const __attribute__((address_space(1))) u32*)g,
                                     (__attribute__((address_space(3))) u32*)l, 16, 0, 0);
}

// ---------------- stage1: transpose_x 64x64 tiles (0..2047) + weight prep (2048..3071) + sc (3072..3135) ----------------
__global__ __launch_bounds__(256) void stage1(const float* __restrict__ x, const float* __restrict__ w1,
                                              const float* __restrict__ w2, const float* __restrict__ s,
                                              const float* __restrict__ c, u16* __restrict__ xT,
                                              u16* __restrict__ o1, u16* __restrict__ o2, u32* __restrict__ scT) {
    __shared__ char smem[16896];
    int bx = blockIdx.x;
    int t = threadIdx.x;
    if (bx < 2048) {
        int lt = bx & 63, ct = (bx >> 6) & 3, b = bx >> 8;
        int l0 = lt * 64, c0 = ct * 64;
        const float* xb = x + ((size_t)b * C_DIM + c0) * N_TOK + l0;
        float* tl = (float*)smem;      // [64 l][65]
#pragma unroll
        for (int i = 0; i < 4; ++i) {
            int id = i * 256 + t;
            int ci = id >> 4, lj = id & 15;
            f32x4 v = *(const f32x4*)(xb + (size_t)ci * N_TOK + lj * 4);
#pragma unroll
            for (int e = 0; e < 4; ++e) tl[(lj * 4 + e) * 65 + ci] = v[e];
        }
        __syncthreads();
#pragma unroll
        for (int j = 0; j < 2; ++j) {
            int id = j * 256 + t;
            int l = id >> 3, cg = id & 7;
            u16 o[8];
#pragma unroll
            for (int e = 0; e < 8; ++e) o[e] = f2bf(tl[l * 65 + cg * 8 + e]);
            uint4 u;
            u.x = (u32)o[0] | ((u32)o[1] << 16);
            u.y = (u32)o[2] | ((u32)o[3] << 16);
            u.z = (u32)o[4] | ((u32)o[5] << 16);
            u.w = (u32)o[6] | ((u32)o[7] << 16);
            *(uint4*)(xT + ((size_t)b * N_TOK + l0 + l) * C_DIM + c0 + cg * 8) = u;
        }
        return;
    }
    int px = bx - 2048;
    if (px < 1024) {
        int i = px * 256 + t;
        o1[i] = f2bf(w1[i]);
        if (i < 256 * 256) o2[i] = f2bf(w2[i]);
        return;
    }
    int l0 = (px - 1024) * 64;
    float (*ts)[33] = (float(*)[33])smem;
    float (*tc)[33] = (float(*)[33])(smem + 8448);
    int d = t & 31, r = t >> 5;
#pragma unroll
    for (int i = 0; i < 8; ++i) {
        ts[r + i * 8][d] = s[(size_t)(l0 + r + i * 8) * HD + d];
        tc[r + i * 8][d] = c[(size_t)(l0 + r + i * 8) * HD + d];
    }
    __syncthreads();
    int li = t & 63, dr = t >> 6;
#pragma unroll
    for (int i = 0; i < 8; ++i) {
        int dd = dr * 8 + i;
        scT[(size_t)dd * N_TOK + l0 + li] = (u32)f2bf(ts[li][dd]) | ((u32)f2bf(tc[li][dd]) << 16);
    }
}

// ---------------- proj GEMM (fp32 out): 128x128 tile, BK=64, XOR slot swizzle ----------------
__global__ __launch_bounds__(256) void gemm_proj(const u16* __restrict__ A, const u16* __restrict__ Bm,
                                                 const float* __restrict__ bias, float* __restrict__ C,
                                                 int M, int L, int K) {
    int bt = blockIdx.z;
    int m0 = blockIdx.y * 128;
    int l0 = blockIdx.x * 128;
    const u16* Bb = Bm + (size_t)bt * L * K;
    float* Cb = C + (size_t)bt * M * L;

    __shared__ u16 smem[17408];
    u16* As = smem;
    u16* Bs = smem + 8192;

    int t = threadIdx.x;
    int w = t >> 6, lane = t & 63;
    int wr = (w >> 1) * 64, wc = (w & 1) * 64;
    int fr = lane & 15, kg = lane >> 4;

    f32x4 acc[4][4] = {};

    for (int k0 = 0; k0 < K; k0 += 64) {
#pragma unroll
        for (int j = 0; j < 4; ++j) {
            int c = j * 256 + w * 64 + lane;
            int row = c >> 3, slot = c & 7;
            int gslot = slot ^ (row & 7);
            u16* abase = As + (size_t)(j * 256 + w * 64) * 8;
            u16* bbase = Bs + (size_t)(j * 256 + w * 64) * 8;
            gload16(A + (size_t)(m0 + row) * K + k0 + gslot * 8, abase);
            gload16(Bb + (size_t)(l0 + row) * K + k0 + gslot * 8, bbase);
        }
        __syncthreads();
#pragma unroll
        for (int kk = 0; kk < 2; ++kk) {
            bf16x8 af[4], bfr[4];
#pragma unroll
            for (int i = 0; i < 4; ++i) {
                int ra = wr + i * 16 + fr;
                int rb = wc + i * 16 + fr;
                af[i]  = *(const bf16x8*)(As + (size_t)ra * 64 + (size_t)((kk * 4 + kg) ^ (ra & 7)) * 8);
                bfr[i] = *(const bf16x8*)(Bs + (size_t)rb * 64 + (size_t)((kk * 4 + kg) ^ (rb & 7)) * 8);
            }
#pragma unroll
            for (int i = 0; i < 4; ++i)
#pragma unroll
                for (int jj = 0; jj < 4; ++jj)
                    acc[i][jj] = __builtin_amdgcn_mfma_f32_16x16x32_bf16(af[i], bfr[jj], acc[i][jj], 0, 0, 0);
        }
        __syncthreads();
    }

    int rg = (lane >> 4) * 4;
    float* Csf = (float*)smem;        // [64][132]
#pragma unroll
    for (int half = 0; half < 2; ++half) {
        if ((w >> 1) == half) {
#pragma unroll
            for (int i = 0; i < 4; ++i)
#pragma unroll
                for (int jj = 0; jj < 4; ++jj) {
                    int col = wc + jj * 16 + fr;
#pragma unroll
                    for (int r = 0; r < 4; ++r) {
                        int row = i * 16 + rg + r;
                        Csf[row * 132 + col] = acc[i][jj][r] + bias[m0 + half * 64 + row];
                    }
                }
        }
        __syncthreads();
#pragma unroll
        for (int j = 0; j < 8; ++j) {
            int id = j * 256 + t;
            int row = id >> 5, c4 = id & 31;
            *(f32x4*)(Cb + (size_t)(m0 + half * 64 + row) * L + l0 + c4 * 4) =
                *(const f32x4*)(Csf + row * 132 + c4 * 4);
        }
        __syncthreads();
    }
}

// ---------------- stage2_kv: fused k/v GEMM + elu/theta + kv outer product; per (chunk, bn) ----------------
__global__ __launch_bounds__(256) void stage2_kv(const u16* __restrict__ wbf, const float* __restrict__ bq,
                                                 const u16* __restrict__ xT, const u32* __restrict__ scT,
                                                 u16* __restrict__ v_glob, float* __restrict__ part_kv,
                                                 float* __restrict__ part_ks, float* __restrict__ part_vs) {
    int chunk = blockIdx.x & 15, bn = blockIdx.x >> 4;
    int b = bn >> 3, n = bn & 7;
    int T0 = chunk * 256;
    const u16* Bx = xT + ((size_t)b * N_TOK + T0) * C_DIM;

    __shared__ char smem[51200];
    u16* Bst = (u16*)smem;                            // [256][64] = 32768
    u16* Ast = (u16*)(smem + 32768);                  // [64][64] = 8192
    u16 (*ks_bf)[264] = (u16(*)[264])smem;            // 16896
    u16 (*v_bf)[264]  = (u16(*)[264])(smem + 16896);  // -> 33792
    float* red  = (float*)(smem + 33792);             // 16384 -> 50176
    float* redk = (float*)(smem + 50176);             // [4][32]
    float* redv = (float*)(smem + 50688);             // [4][32]

    int t = threadIdx.x;
    int w = t >> 6, lane = t & 63;
    int fr = lane & 15, kg = lane >> 4;

    float bk[8], bv[8];
#pragma unroll
    for (int i = 0; i < 2; ++i)
#pragma unroll
        for (int r = 0; r < 4; ++r) {
            bk[i * 4 + r] = bq[256 + n * HD + i * 16 + kg * 4 + r];
            bv[i * 4 + r] = bq[512 + n * HD + i * 16 + kg * 4 + r];
        }

    // ---- phase 0: GEMM 64 rows (k:0..31, v:32..63) x 256 tokens, K=256 ----
    f32x4 acc[4][4] = {};
    for (int k0 = 0; k0 < 256; k0 += 64) {
#pragma unroll
        for (int j = 0; j < 8; ++j) {
            int cc = j * 256 + w * 64 + lane;
            int row = cc >> 3, slot = cc & 7;
            int gslot = slot ^ (row & 7);
            gload16(Bx + (size_t)row * C_DIM + k0 + gslot * 8, Bst + (size_t)(j * 256 + w * 64) * 8);
        }
#pragma unroll
        for (int j = 0; j < 2; ++j) {
            int cc = j * 256 + w * 64 + lane;
            int row = cc >> 3, slot = cc & 7;
            int gslot = slot ^ (row & 7);
            int arow = (row < 32 ? 256 : 480) + n * HD + row;
            gload16(wbf + (size_t)arow * C_DIM + k0 + gslot * 8, Ast + (size_t)(j * 256 + w * 64) * 8);
        }
        __syncthreads();
#pragma unroll
        for (int kk = 0; kk < 2; ++kk) {
            bf16x8 af[4], bfr[4];
#pragma unroll
            for (int i = 0; i < 4; ++i) {
                int ra = i * 16 + fr;
                af[i] = *(const bf16x8*)(Ast + (size_t)ra * 64 + (size_t)((kk * 4 + kg) ^ (ra & 7)) * 8);
            }
#pragma unroll
            for (int jj = 0; jj < 4; ++jj) {
                int rb = w * 64 + jj * 16 + fr;
                bfr[jj] = *(const bf16x8*)(Bst + (size_t)rb * 64 + (size_t)((kk * 4 + kg) ^ (rb & 7)) * 8);
            }
#pragma unroll
            for (int i = 0; i < 4; ++i)
#pragma unroll
                for (int jj = 0; jj < 4; ++jj)
                    acc[i][jj] = __builtin_amdgcn_mfma_f32_16x16x32_bf16(af[i], bfr[jj], acc[i][jj], 0, 0, 0);
        }
        __syncthreads();
    }

    // ---- scatter: k -> elu+ksum+theta -> ks_bf; v -> vsum -> v_bf ----
    float kspart[8] = {}, vspart[8] = {};
#pragma unroll
    for (int i = 0; i < 2; ++i)
#pragma unroll
        for (int jj = 0; jj < 4; ++jj) {
            int tok = w * 64 + jj * 16 + fr;
            float k0v = acc[i][jj][0] + bk[i * 4 + 0];
            float k1v = acc[i][jj][1] + bk[i * 4 + 1];
            float k2v = acc[i][jj][2] + bk[i * 4 + 2];
            float k3v = acc[i][jj][3] + bk[i * 4 + 3];
            float e0 = k0v > 0.f ? k0v + 1.f : __expf(k0v);
            float e1 = k1v > 0.f ? k1v + 1.f : __expf(k1v);
            float e2 = k2v > 0.f ? k2v + 1.f : __expf(k2v);
            float e3 = k3v > 0.f ? k3v + 1.f : __expf(k3v);
            kspart[i * 4 + 0] += e0; kspart[i * 4 + 1] += e1;
            kspart[i * 4 + 2] += e2; kspart[i * 4 + 3] += e3;
            int d0 = i * 16 + kg * 4;
            u32 sA = scT[(size_t)(d0 + 0) * N_TOK + T0 + tok];
            u32 sB = scT[(size_t)(d0 + 1) * N_TOK + T0 + tok];
            u32 sC = scT[(size_t)(d0 + 2) * N_TOK + T0 + tok];
            u32 sD = scT[(size_t)(d0 + 3) * N_TOK + T0 + tok];
            ks_bf[d0 + 0][tok] = f2bf(e0 * bf_hi(sA) - e1 * bf_lo(sA));
            ks_bf[d0 + 1][tok] = f2bf(e1 * bf_hi(sB) + e0 * bf_lo(sB));
            ks_bf[d0 + 2][tok] = f2bf(e2 * bf_hi(sC) - e3 * bf_lo(sC));
            ks_bf[d0 + 3][tok] = f2bf(e3 * bf_hi(sD) + e2 * bf_lo(sD));
        }
#pragma unroll
    for (int i = 2; i < 4; ++i)
#pragma unroll
        for (int jj = 0; jj < 4; ++jj) {
            int tok = w * 64 + jj * 16 + fr;
#pragma unroll
            for (int r = 0; r < 4; ++r) {
                int vrow = (i - 2) * 16 + kg * 4 + r;
                float vv_ = acc[i][jj][r] + bv[(i - 2) * 4 + r];
                vspart[(i - 2) * 4 + r] += vv_;
                v_bf[vrow][tok] = f2bf(vv_);
            }
        }
#pragma unroll
    for (int m = 1; m < 16; m <<= 1) {
#pragma unroll
        for (int q = 0; q < 8; ++q) {
            kspart[q] += __shfl_xor(kspart[q], m);
            vspart[q] += __shfl_xor(vspart[q], m);
        }
    }
    if (fr == 0) {
#pragma unroll
        for (int q = 0; q < 8; ++q) {
            int row = (q >> 2) * 16 + kg * 4 + (q & 3);
            redk[w * 32 + row] = kspart[q];
            redv[w * 32 + row] = vspart[q];
        }
    }
    __syncthreads();

    // ---- MFMA outer product over 256 tokens; wave w -> tokens w*64..+63 ----
    f32x4 a2[2][2] = {};
#pragma unroll
    for (int kc = 0; kc < 2; ++kc) {
        int kcol = w * 64 + kc * 32 + kg * 8;
        bf16x8 af[2], bfv[2];
#pragma unroll
        for (int i = 0; i < 2; ++i) {
            af[i]  = *(const bf16x8*)&ks_bf[i * 16 + fr][kcol];
            bfv[i] = *(const bf16x8*)&v_bf[i * 16 + fr][kcol];
        }
#pragma unroll
        for (int i = 0; i < 2; ++i)
#pragma unroll
            for (int jj = 0; jj < 2; ++jj)
                a2[i][jj] = __builtin_amdgcn_mfma_f32_16x16x32_bf16(af[i], bfv[jj], a2[i][jj], 0, 0, 0);
    }

    // ---- cooperative v -> global (for lepe) ----
    {
        int row = t >> 3, tg = t & 7;
        u16* vg = v_glob + ((size_t)(b * C_DIM + n * HD + row)) * N_TOK + T0 + tg * 32;
#pragma unroll
        for (int q = 0; q < 4; ++q)
            *(uint4*)(vg + q * 8) = *(const uint4*)&v_bf[row][tg * 32 + q * 8];
    }
    if (t < 32) {
        float s = redk[t] + redk[32 + t] + redk[64 + t] + redk[96 + t];
        float sv = redv[t] + redv[32 + t] + redv[64 + t] + redv[96 + t];
        part_ks[((size_t)bn * 16 + chunk) * 32 + t] = s;
        part_vs[((size_t)bn * 16 + chunk) * 32 + t] = sv;
    }

#pragma unroll
    for (int i = 0; i < 2; ++i)
#pragma unroll
        for (int jj = 0; jj < 2; ++jj)
#pragma unroll
            for (int r = 0; r < 4; ++r) {
                int row = i * 16 + kg * 4 + r;
                int col = jj * 16 + fr;
                red[w * 1024 + row * 32 + col] = a2[i][jj][r];
            }
    __syncthreads();
    float* pkv = part_kv + ((size_t)bn * 16 + chunk) * 1024;
#pragma unroll
    for (int i = 0; i < 4; ++i) {
        int el = i * 256 + t;
        pkv[el] = red[el] + red[1024 + el] + red[2048 + el] + red[3072 + el];
    }
}

// ---------------- kv_final (blocks 0..63) + lepe (blocks 64..2111) ----------------
__global__ __launch_bounds__(256) void kvfinal_lepe(const float* __restrict__ part_kv, const float* __restrict__ part_ks,
                                                    const float* __restrict__ part_vs, const u16* __restrict__ v_glob,
                                                    const float* __restrict__ wl, const float* __restrict__ bl,
                                                    u16* __restrict__ kvT_bf, float* __restrict__ kmean,
                                                    float* __restrict__ vmean, u16* __restrict__ lepe) {
    __shared__ float wc5[25];
    int bx = blockIdx.x;
    int t = threadIdx.x;
    if (bx < 64) {
        int bn = bx;
        const float* p = part_kv + (size_t)bn * 16 * 1024;
        const float s2c = SCALE_F / (float)N_TOK;
#pragma unroll
        for (int i = 0; i < 4; ++i) {
            int sl = t + i * 256;
            float s = 0;
#pragma unroll
            for (int c = 0; c < 16; ++c) s += p[(size_t)c * 1024 + sl];
            float val = s * s2c;
            int d = sl >> 5, e = sl & 31;
            kvT_bf[(size_t)bn * 1024 + e * 32 + d] = f2bf(val);
        }
        if (t < 32) {
            float s = 0, sv = 0;
            for (int c = 0; c < 16; ++c) {
                s  += part_ks[((size_t)bn * 16 + c) * 32 + t];
                sv += part_vs[((size_t)bn * 16 + c) * 32 + t];
            }
            kmean[bn * 32 + t] = s * (1.f / (float)N_TOK);
            vmean[bn * 32 + t] = sv * (1.f / (float)N_TOK);
        }
        return;
    }
    int i2 = bx - 64;
    int c = i2 & 255, b = i2 >> 8;
    const u16* src = v_glob + ((size_t)(b * C_DIM + c)) * N_TOK;
    u16* dst = lepe + ((size_t)b * C_DIM + c) * N_TOK;
    if (t < 25) wc5[t] = wl[c * 25 + t];
    __syncthreads();

    int h = t >> 2, w0 = (t & 3) * 16;
    float bb = bl[c];
    float o16[16];
#pragma unroll
    for (int i = 0; i < 16; ++i) o16[i] = bb;

#pragma unroll
    for (int dh = 0; dh < 5; ++dh) {
        int gr = h + dh - 2;
        bool rowok = (gr >= 0) && (gr < 64);
        const u16* rp = src + (size_t)(rowok ? gr : 0) * 64 + w0 - 8;
        bf16x8 L0 = ((const bf16x8*)rp)[0];
        bf16x8 L1 = ((const bf16x8*)rp)[1];
        bf16x8 L2 = ((const bf16x8*)rp)[2];
        bf16x8 L3 = ((const bf16x8*)rp)[3];
        float rbuf[32];
#pragma unroll
        for (int j = 0; j < 32; ++j) {
            int col = w0 - 8 + j;
            u16 raw = (u16)(j < 8 ? L0[j] : j < 16 ? L1[j - 8] : j < 24 ? L2[j - 16] : L3[j - 24]);
            bool ok = rowok && (col >= 0) && (col < 64);
            rbuf[j] = ok ? b2f(raw) : 0.f;
        }
#pragma unroll
        for (int dw = 0; dw < 5; ++dw) {
            float wv_ = wc5[dh * 5 + dw];
#pragma unroll
            for (int ow = 0; ow < 16; ++ow)
                o16[ow] += rbuf[6 + dw + ow] * wv_;
        }
    }

    uint4 u0, u1;
    u0.x = (u32)f2bf(o16[0]) | ((u32)f2bf(o16[1]) << 16);
    u0.y = (u32)f2bf(o16[2]) | ((u32)f2bf(o16[3]) << 16);
    u0.z = (u32)f2bf(o16[4]) | ((u32)f2bf(o16[5]) << 16);
    u0.w = (u32)f2bf(o16[6]) | ((u32)f2bf(o16[7]) << 16);
    u1.x = (u32)f2bf(o16[8]) | ((u32)f2bf(o16[9]) << 16);
    u1.y = (u32)f2bf(o16[10]) | ((u32)f2bf(o16[11]) << 16);
    u1.z = (u32)f2bf(o16[12]) | ((u32)f2bf(o16[13]) << 16);
    u1.w = (u32)f2bf(o16[14]) | ((u32)f2bf(o16[15]) << 16);
    *(uint4*)(dst + h * 64 + w0) = u0;
    *(uint4*)(dst + h * 64 + w0 + 8) = u1;
}

// ---------------- attention epilogue (r12 structure, Rt aliased onto qA -> 43.8 KB LDS, 3 blocks/CU) ----------------
__global__ __launch_bounds__(256, 3) void attn_epilogue(const u16* __restrict__ wbf, const float* __restrict__ bq,
                                                        const u16* __restrict__ xT, const u32* __restrict__ scT,
                                                        const u16* __restrict__ kvT_bf, const float* __restrict__ kmean,
                                                        const float* __restrict__ vmean, const u16* __restrict__ lepe,
                                                        u16* __restrict__ resnT) {
    int lt = blockIdx.x, bn = blockIdx.y;
    int b = bn >> 3, n = bn & 7;
    int T0 = lt * 256;
    const u16* lp = lepe + ((size_t)b * C_DIM + n * HD) * N_TOK;
    const u16* Bx = xT + ((size_t)b * N_TOK + T0) * C_DIM;

    __shared__ char smem[43776];
    // staging (phase0 only): Bst @0 (32768), Ast @32768 (8192) -> 40960
    // compute: qA @0 [256][40] (20480) — ALSO serves as Rt (per-wave region identical);
    //          o_lds @20480 (20480); kvb @40960 (2560); kml @43520 (128); vml @43648 (128)
    u16* qA    = (u16*)smem;
    u16* o_lds = (u16*)(smem + 20480);
    u16* Rt    = (u16*)smem;              // alias of qA (safe: per-wave reads complete before writes)
    u16* kvb   = (u16*)(smem + 40960);
    float* kml = (float*)(smem + 43520);
    float* vml = (float*)(smem + 43648);
    u16* Bst = (u16*)smem;
    u16* Ast = (u16*)(smem + 32768);

    int t = threadIdx.x;
    int w = t >> 6, lane = t & 63;
    int fr = lane & 15, kg = lane >> 4;

    if (t < 128) {
        int e = t >> 2, d0 = (t & 3) * 8;
        *(uint4*)(kvb + e * 40 + d0) = *(const uint4*)(kvT_bf + (size_t)bn * 1024 + e * 32 + d0);
    }
    if (t < 32) { kml[t] = kmean[bn * 32 + t]; vml[t] = vmean[bn * 32 + t]; }

    // ---- phase 0: GEMM q,o = W_qo x xT^T ----
    f32x4 acc[4][4] = {};
    for (int k0 = 0; k0 < 256; k0 += 64) {
#pragma unroll
        for (int j = 0; j < 8; ++j) {
            int cc = j * 256 + w * 64 + lane;
            int row = cc >> 3, slot = cc & 7;
            int gslot = slot ^ (row & 7);
            gload16(Bx + (size_t)row * C_DIM + k0 + gslot * 8, Bst + (size_t)(j * 256 + w * 64) * 8);
        }
#pragma unroll
        for (int j = 0; j < 2; ++j) {
            int cc = j * 256 + w * 64 + lane;
            int row = cc >> 3, slot = cc & 7;
            int gslot = slot ^ (row & 7);
            int arow = (row < 32 ? n * HD : 736 + n * HD) + row;
            gload16(wbf + (size_t)arow * C_DIM + k0 + gslot * 8, Ast + (size_t)(j * 256 + w * 64) * 8);
        }
        __syncthreads();
#pragma unroll
        for (int kk = 0; kk < 2; ++kk) {
            bf16x8 af[4], bfr[4];
#pragma unroll
            for (int i = 0; i < 4; ++i) {
                int ra = i * 16 + fr;
                af[i] = *(const bf16x8*)(Ast + (size_t)ra * 64 + (size_t)((kk * 4 + kg) ^ (ra & 7)) * 8);
            }
#pragma unroll
            for (int jj = 0; jj < 4; ++jj) {
                int rb = w * 64 + jj * 16 + fr;
                bfr[jj] = *(const bf16x8*)(Bst + (size_t)rb * 64 + (size_t)((kk * 4 + kg) ^ (rb & 7)) * 8);
            }
#pragma unroll
            for (int i = 0; i < 4; ++i)
#pragma unroll
                for (int jj = 0; jj < 4; ++jj)
                    acc[i][jj] = __builtin_amdgcn_mfma_f32_16x16x32_bf16(af[i], bfr[jj], acc[i][jj], 0, 0, 0);
        }
        __syncthreads();
    }
    // scatter q (rows 0..31) / o (rows 32..63) as [tok][row] bf16
    int rg = kg * 4;
#pragma unroll
    for (int i = 0; i < 4; ++i)
#pragma unroll
        for (int jj = 0; jj < 4; ++jj) {
            int tok = w * 64 + jj * 16 + fr;
#pragma unroll
            for (int r = 0; r < 4; ++r) {
                int qorow = i * 16 + rg + r;
                int brow = (qorow < 32 ? n * HD : 736 + n * HD) + qorow;
                u16 val = f2bf(acc[i][jj][r] + bq[brow]);
                if (qorow < 32) qA[tok * 40 + qorow] = val;
                else            o_lds[tok * 40 + qorow - 32] = val;
            }
        }
    __syncthreads();

    // ---- phase 1: per-token elu / z / theta -> q' A-tile (in place) ----
    int token = T0 + t;
    float qv[32];
    float z = 0.f;
#pragma unroll
    for (int j = 0; j < 4; ++j) {
        bf16x8 q8 = *(const bf16x8*)(qA + t * 40 + j * 8);
#pragma unroll
        for (int e = 0; e < 8; ++e) {
            float x_ = b2f((u16)q8[e]);
            float e_ = x_ > 0.f ? x_ + 1.f : __expf(x_);
            qv[j * 8 + e] = e_;
            z += e_ * kml[j * 8 + e];
        }
    }
    z *= SCALE_F;
#pragma unroll
    for (int p = 0; p < 16; ++p) {
        u32 sc0 = scT[(size_t)(2 * p) * N_TOK + token];
        u32 sc1 = scT[(size_t)(2 * p + 1) * N_TOK + token];
        float se = bf_lo(sc0), ce = bf_hi(sc0);
        float so = bf_lo(sc1), co = bf_hi(sc1);
        float a = qv[2 * p], bb = qv[2 * p + 1];
        qv[2 * p]     = a * ce - bb * se;
        qv[2 * p + 1] = bb * co + a * so;
    }
    float mult = 1.f + 1.f / (z + 1e-6f);
#pragma unroll
    for (int j4 = 0; j4 < 4; ++j4) {
        uint4 u;
        u.x = (u32)f2bf(qv[8 * j4 + 0]) | ((u32)f2bf(qv[8 * j4 + 1]) << 16);
        u.y = (u32)f2bf(qv[8 * j4 + 2]) | ((u32)f2bf(qv[8 * j4 + 3]) << 16);
        u.z = (u32)f2bf(qv[8 * j4 + 4]) | ((u32)f2bf(qv[8 * j4 + 5]) << 16);
        u.w = (u32)f2bf(qv[8 * j4 + 6]) | ((u32)f2bf(qv[8 * j4 + 7]) << 16);
        *(uint4*)(qA + t * 40 + j4 * 8) = u;
    }
    __syncthreads();

    // ---- phase 2: matvec q' x kv^T (reads hoisted to VGPRs before aliased writes) ----
    {
        bf16x8 af[4], bfr[2];
#pragma unroll
        for (int i = 0; i < 4; ++i)
            af[i] = *(const bf16x8*)(qA + (size_t)(w * 64 + i * 16 + fr) * 40 + kg * 8);
#pragma unroll
        for (int jj = 0; jj < 2; ++jj)
            bfr[jj] = *(const bf16x8*)(kvb + (jj * 16 + fr) * 40 + kg * 8);

        u16* Rw = Rt + w * 2560;
        f32x4 zero = {0.f, 0.f, 0.f, 0.f};
#pragma unroll
        for (int i = 0; i < 4; ++i)
#pragma unroll
            for (int jj = 0; jj < 2; ++jj) {
                f32x4 a2 = __builtin_amdgcn_mfma_f32_16x16x32_bf16(af[i], bfr[jj], zero, 0, 0, 0);
#pragma unroll
                for (int r = 0; r < 4; ++r)
                    Rw[(i * 16 + kg * 4 + r) * 40 + jj * 16 + fr] = f2bf(a2[r]);
            }
    }
    __syncthreads();

    // ---- phase 3: finish ----
    float res[32], ovv[32];
#pragma unroll
    for (int j = 0; j < 4; ++j) {
        bf16x8 r8 = *(const bf16x8*)(Rt + w * 2560 + lane * 40 + j * 8);
        bf16x8 o8 = *(const bf16x8*)(o_lds + t * 40 + j * 8);
#pragma unroll
        for (int e = 0; e < 8; ++e) {
            res[j * 8 + e] = b2f((u16)r8[e]);
            ovv[j * 8 + e] = b2f((u16)o8[e]);
        }
    }

    u16* dst0 = resnT + ((size_t)b * N_TOK + token) * C_DIM + n * HD;
#pragma unroll
    for (int g = 0; g < 4; ++g) {
        float vv[8];
#pragma unroll
        for (int e2 = 0; e2 < 8; ++e2) {
            int ee = g * 8 + e2;
            float lx = b2f(lp[(size_t)ee * N_TOK + token]);
            float rx = res[ee] * mult - z * vml[ee];
            vv[e2] = (rx + lx) * ovv[ee];
        }
        uint4 u;
        u.x = (u32)f2bf(vv[0]) | ((u32)f2bf(vv[1]) << 16);
        u.y = (u32)f2bf(vv[2]) | ((u32)f2bf(vv[3]) << 16);
        u.z = (u32)f2bf(vv[4]) | ((u32)f2bf(vv[5]) << 16);
        u.w = (u32)f2bf(vv[6]) | ((u32)f2bf(vv[7]) << 16);
        ((uint4*)(dst0 + g * 8))[0] = u;
    }
}

extern "C" void kernel_launch(void* const* d_in, const int* in_sizes, int n_in,
                              void* d_out, int out_size, void* d_ws, size_t ws_size,
                              hipStream_t stream) {
    const float* x      = (const float*)d_in[0];
    const float* sinp   = (const float*)d_in[1];
    const float* cosp   = (const float*)d_in[2];
    const float* w_qkvo = (const float*)d_in[3];
    const float* b_qkvo = (const float*)d_in[4];
    const float* w_lepe = (const float*)d_in[5];
    const float* b_lepe = (const float*)d_in[6];
    const float* w_proj = (const float*)d_in[7];
    const float* b_proj = (const float*)d_in[8];

    char* ws = (char*)d_ws;
    size_t off = 0;
    auto alloc = [&](size_t bytes) { size_t o = off; off = (off + bytes + 255) & ~(size_t)255; return o; };
    u16*   wbf     = (u16*)(ws + alloc((size_t)1024 * 256 * 2));
    u16*   wpbf    = (u16*)(ws + alloc((size_t)256 * 256 * 2));
    u16*   xT      = (u16*)(ws + alloc((size_t)8 * 4096 * 256 * 2));
    u16*   v_glob  = (u16*)(ws + alloc((size_t)8 * 256 * 4096 * 2));
    u16*   lepe    = (u16*)(ws + alloc((size_t)8 * 256 * 4096 * 2));
    u16*   resnT   = (u16*)(ws + alloc((size_t)8 * 4096 * 256 * 2));
    float* part_kv = (float*)(ws + alloc((size_t)64 * 16 * 1024 * 4));
    float* part_ks = (float*)(ws + alloc((size_t)64 * 16 * 32 * 4));
    float* part_vs = (float*)(ws + alloc((size_t)64 * 16 * 32 * 4));
    u16*   kvT_bf  = (u16*)(ws + alloc((size_t)64 * 1024 * 2));
    float* kmean   = (float*)(ws + alloc((size_t)64 * 32 * 4));
    float* vmean   = (float*)(ws + alloc((size_t)64 * 32 * 4));
    u32*   scT     = (u32*)(ws + alloc((size_t)32 * 4096 * 4));
    if (off > ws_size) return;  // insufficient workspace -> loud validation failure

    stage1<<<dim3(3136), dim3(256), 0, stream>>>(x, w_qkvo, w_proj, sinp, cosp, xT, wbf, wpbf, scT);
    stage2_kv<<<dim3(1024), dim3(256), 0, stream>>>(wbf, b_qkvo, xT, scT, v_glob, part_kv, part_ks, part_vs);
    kvfinal_lepe<<<dim3(2112), dim3(256), 0, stream>>>(part_kv, part_ks, part_vs, v_glob, w_lepe, b_lepe,
                                                       kvT_bf, kmean, vmean, lepe);
    attn_epilogue<<<dim3(16, 64), dim3(256), 0, stream>>>(wbf, b_qkvo, xT, scT, kvT_bf, kmean, vmean, lepe, resnT);
    gemm_proj<<<dim3(32, 2, 8), dim3(256), 0, stream>>>(wpbf, resnT, b_proj, (float*)d_out, 256, 4096, 256);
}

// Round 17
// 92.752 us; speedup vs baseline: 1.0831x; 1.0102x over previous
//
#include <hip/hip_runtime.h>
#include <hip/hip_bf16.h>

typedef unsigned short u16;
typedef unsigned int u32;
typedef short bf16x8 __attribute__((ext_vector_type(8)));
typedef float f32x4 __attribute__((ext_vector_type(4)));
typedef u32 u32x4 __attribute__((ext_vector_type(4)));

#define N_TOK 4096
#define C_DIM 256
#define HEADS 8
#define HD 32
#define SCALE_F 0.17677669529663687f   /* 32^-0.5 */

__device__ inline u16 f2bf(float f) {
    u32 u = __float_as_uint(f);
    u += 0x7fffu + ((u >> 16) & 1u);
    return (u16)(u >> 16);
}
__device__ inline float b2f(u16 h) { return __uint_as_float((u32)h << 16); }
__device__ inline float bf_lo(u32 u) { return __uint_as_float(u << 16); }
__device__ inline float bf_hi(u32 u) { return __uint_as_float(u & 0xffff0000u); }

__device__ inline void gload16(const void* g, void* l) {
    __builtin_amdgcn_global_load_lds((const __attribute__((address_space(1))) u32*)g,
                                     (__attribute__((address_space(3))) u32*)l, 16, 0, 0);
}

// ---------------- stage1: transpose_x 64x64 tiles (0..2047) + weight prep (2048..3071) + sc (3072..3135) ----------------
__global__ __launch_bounds__(256) void stage1(const float* __restrict__ x, const float* __restrict__ w1,
                                              const float* __restrict__ w2, const float* __restrict__ s,
                                              const float* __restrict__ c, u16* __restrict__ xT,
                                              u16* __restrict__ o1, u16* __restrict__ o2, u32* __restrict__ scT) {
    __shared__ char smem[16896];
    int bx = blockIdx.x;
    int t = threadIdx.x;
    if (bx < 2048) {
        int lt = bx & 63, ct = (bx >> 6) & 3, b = bx >> 8;
        int l0 = lt * 64, c0 = ct * 64;
        const float* xb = x + ((size_t)b * C_DIM + c0) * N_TOK + l0;
        float* tl = (float*)smem;      // [64 l][65]
#pragma unroll
        for (int i = 0; i < 4; ++i) {
            int id = i * 256 + t;
            int ci = id >> 4, lj = id & 15;
            f32x4 v = *(const f32x4*)(xb + (size_t)ci * N_TOK + lj * 4);
#pragma unroll
            for (int e = 0; e < 4; ++e) tl[(lj * 4 + e) * 65 + ci] = v[e];
        }
        __syncthreads();
#pragma unroll
        for (int j = 0; j < 2; ++j) {
            int id = j * 256 + t;
            int l = id >> 3, cg = id & 7;
            u16 o[8];
#pragma unroll
            for (int e = 0; e < 8; ++e) o[e] = f2bf(tl[l * 65 + cg * 8 + e]);
            uint4 u;
            u.x = (u32)o[0] | ((u32)o[1] << 16);
            u.y = (u32)o[2] | ((u32)o[3] << 16);
            u.z = (u32)o[4] | ((u32)o[5] << 16);
            u.w = (u32)o[6] | ((u32)o[7] << 16);
            *(uint4*)(xT + ((size_t)b * N_TOK + l0 + l) * C_DIM + c0 + cg * 8) = u;
        }
        return;
    }
    int px = bx - 2048;
    if (px < 1024) {
        int i = px * 256 + t;
        o1[i] = f2bf(w1[i]);
        if (i < 256 * 256) o2[i] = f2bf(w2[i]);
        return;
    }
    int l0 = (px - 1024) * 64;
    float (*ts)[33] = (float(*)[33])smem;
    float (*tc)[33] = (float(*)[33])(smem + 8448);
    int d = t & 31, r = t >> 5;
#pragma unroll
    for (int i = 0; i < 8; ++i) {
        ts[r + i * 8][d] = s[(size_t)(l0 + r + i * 8) * HD + d];
        tc[r + i * 8][d] = c[(size_t)(l0 + r + i * 8) * HD + d];
    }
    __syncthreads();
    int li = t & 63, dr = t >> 6;
#pragma unroll
    for (int i = 0; i < 8; ++i) {
        int dd = dr * 8 + i;
        scT[(size_t)dd * N_TOK + l0 + li] = (u32)f2bf(ts[li][dd]) | ((u32)f2bf(tc[li][dd]) << 16);
    }
}

// ---------------- proj GEMM (fp32 out): 128x128 tile, BK=64, XOR slot swizzle ----------------
__global__ __launch_bounds__(256) void gemm_proj(const u16* __restrict__ A, const u16* __restrict__ Bm,
                                                 const float* __restrict__ bias, float* __restrict__ C,
                                                 int M, int L, int K) {
    int bt = blockIdx.z;
    int m0 = blockIdx.y * 128;
    int l0 = blockIdx.x * 128;
    const u16* Bb = Bm + (size_t)bt * L * K;
    float* Cb = C + (size_t)bt * M * L;

    __shared__ u16 smem[17408];
    u16* As = smem;
    u16* Bs = smem + 8192;

    int t = threadIdx.x;
    int w = t >> 6, lane = t & 63;
    int wr = (w >> 1) * 64, wc = (w & 1) * 64;
    int fr = lane & 15, kg = lane >> 4;

    f32x4 acc[4][4] = {};

    for (int k0 = 0; k0 < K; k0 += 64) {
#pragma unroll
        for (int j = 0; j < 4; ++j) {
            int c = j * 256 + w * 64 + lane;
            int row = c >> 3, slot = c & 7;
            int gslot = slot ^ (row & 7);
            u16* abase = As + (size_t)(j * 256 + w * 64) * 8;
            u16* bbase = Bs + (size_t)(j * 256 + w * 64) * 8;
            gload16(A + (size_t)(m0 + row) * K + k0 + gslot * 8, abase);
            gload16(Bb + (size_t)(l0 + row) * K + k0 + gslot * 8, bbase);
        }
        __syncthreads();
#pragma unroll
        for (int kk = 0; kk < 2; ++kk) {
            bf16x8 af[4], bfr[4];
#pragma unroll
            for (int i = 0; i < 4; ++i) {
                int ra = wr + i * 16 + fr;
                int rb = wc + i * 16 + fr;
                af[i]  = *(const bf16x8*)(As + (size_t)ra * 64 + (size_t)((kk * 4 + kg) ^ (ra & 7)) * 8);
                bfr[i] = *(const bf16x8*)(Bs + (size_t)rb * 64 + (size_t)((kk * 4 + kg) ^ (rb & 7)) * 8);
            }
#pragma unroll
            for (int i = 0; i < 4; ++i)
#pragma unroll
                for (int jj = 0; jj < 4; ++jj)
                    acc[i][jj] = __builtin_amdgcn_mfma_f32_16x16x32_bf16(af[i], bfr[jj], acc[i][jj], 0, 0, 0);
        }
        __syncthreads();
    }

    int rg = (lane >> 4) * 4;
    float* Csf = (float*)smem;        // [64][132]
#pragma unroll
    for (int half = 0; half < 2; ++half) {
        if ((w >> 1) == half) {
#pragma unroll
            for (int i = 0; i < 4; ++i)
#pragma unroll
                for (int jj = 0; jj < 4; ++jj) {
                    int col = wc + jj * 16 + fr;
#pragma unroll
                    for (int r = 0; r < 4; ++r) {
                        int row = i * 16 + rg + r;
                        Csf[row * 132 + col] = acc[i][jj][r] + bias[m0 + half * 64 + row];
                    }
                }
        }
        __syncthreads();
#pragma unroll
        for (int j = 0; j < 8; ++j) {
            int id = j * 256 + t;
            int row = id >> 5, c4 = id & 31;
            *(f32x4*)(Cb + (size_t)(m0 + half * 64 + row) * L + l0 + c4 * 4) =
                *(const f32x4*)(Csf + row * 132 + c4 * 4);
        }
        __syncthreads();
    }
}

// ---------------- stage2_kv: fused k/v GEMM + elu/theta + kv outer product; per (chunk, bn) ----------------
__global__ __launch_bounds__(256) void stage2_kv(const u16* __restrict__ wbf, const float* __restrict__ bq,
                                                 const u16* __restrict__ xT, const u32* __restrict__ scT,
                                                 u16* __restrict__ v_glob, float* __restrict__ part_kv,
                                                 float* __restrict__ part_ks, float* __restrict__ part_vs) {
    int chunk = blockIdx.x & 15, bn = blockIdx.x >> 4;
    int b = bn >> 3, n = bn & 7;
    int T0 = chunk * 256;
    const u16* Bx = xT + ((size_t)b * N_TOK + T0) * C_DIM;

    __shared__ char smem[51200];
    u16* Bst = (u16*)smem;                            // [256][64] = 32768
    u16* Ast = (u16*)(smem + 32768);                  // [64][64] = 8192
    u16 (*ks_bf)[264] = (u16(*)[264])smem;            // 16896
    u16 (*v_bf)[264]  = (u16(*)[264])(smem + 16896);  // -> 33792
    float* red  = (float*)(smem + 33792);             // 16384 -> 50176
    float* redk = (float*)(smem + 50176);             // [4][32]
    float* redv = (float*)(smem + 50688);             // [4][32]

    int t = threadIdx.x;
    int w = t >> 6, lane = t & 63;
    int fr = lane & 15, kg = lane >> 4;

    float bk[8], bv[8];
#pragma unroll
    for (int i = 0; i < 2; ++i)
#pragma unroll
        for (int r = 0; r < 4; ++r) {
            bk[i * 4 + r] = bq[256 + n * HD + i * 16 + kg * 4 + r];
            bv[i * 4 + r] = bq[512 + n * HD + i * 16 + kg * 4 + r];
        }

    // ---- phase 0: GEMM 64 rows (k:0..31, v:32..63) x 256 tokens, K=256 ----
    f32x4 acc[4][4] = {};
    for (int k0 = 0; k0 < 256; k0 += 64) {
#pragma unroll
        for (int j = 0; j < 8; ++j) {
            int cc = j * 256 + w * 64 + lane;
            int row = cc >> 3, slot = cc & 7;
            int gslot = slot ^ (row & 7);
            gload16(Bx + (size_t)row * C_DIM + k0 + gslot * 8, Bst + (size_t)(j * 256 + w * 64) * 8);
        }
#pragma unroll
        for (int j = 0; j < 2; ++j) {
            int cc = j * 256 + w * 64 + lane;
            int row = cc >> 3, slot = cc & 7;
            int gslot = slot ^ (row & 7);
            int arow = (row < 32 ? 256 : 480) + n * HD + row;
            gload16(wbf + (size_t)arow * C_DIM + k0 + gslot * 8, Ast + (size_t)(j * 256 + w * 64) * 8);
        }
        __syncthreads();
#pragma unroll
        for (int kk = 0; kk < 2; ++kk) {
            bf16x8 af[4], bfr[4];
#pragma unroll
            for (int i = 0; i < 4; ++i) {
                int ra = i * 16 + fr;
                af[i] = *(const bf16x8*)(Ast + (size_t)ra * 64 + (size_t)((kk * 4 + kg) ^ (ra & 7)) * 8);
            }
#pragma unroll
            for (int jj = 0; jj < 4; ++jj) {
                int rb = w * 64 + jj * 16 + fr;
                bfr[jj] = *(const bf16x8*)(Bst + (size_t)rb * 64 + (size_t)((kk * 4 + kg) ^ (rb & 7)) * 8);
            }
#pragma unroll
            for (int i = 0; i < 4; ++i)
#pragma unroll
                for (int jj = 0; jj < 4; ++jj)
                    acc[i][jj] = __builtin_amdgcn_mfma_f32_16x16x32_bf16(af[i], bfr[jj], acc[i][jj], 0, 0, 0);
        }
        __syncthreads();
    }

    // ---- scatter: k -> elu+ksum+theta -> ks_bf; v -> vsum -> v_bf ----
    float kspart[8] = {}, vspart[8] = {};
#pragma unroll
    for (int i = 0; i < 2; ++i)
#pragma unroll
        for (int jj = 0; jj < 4; ++jj) {
            int tok = w * 64 + jj * 16 + fr;
            float k0v = acc[i][jj][0] + bk[i * 4 + 0];
            float k1v = acc[i][jj][1] + bk[i * 4 + 1];
            float k2v = acc[i][jj][2] + bk[i * 4 + 2];
            float k3v = acc[i][jj][3] + bk[i * 4 + 3];
            float e0 = k0v > 0.f ? k0v + 1.f : __expf(k0v);
            float e1 = k1v > 0.f ? k1v + 1.f : __expf(k1v);
            float e2 = k2v > 0.f ? k2v + 1.f : __expf(k2v);
            float e3 = k3v > 0.f ? k3v + 1.f : __expf(k3v);
            kspart[i * 4 + 0] += e0; kspart[i * 4 + 1] += e1;
            kspart[i * 4 + 2] += e2; kspart[i * 4 + 3] += e3;
            int d0 = i * 16 + kg * 4;
            u32 sA = scT[(size_t)(d0 + 0) * N_TOK + T0 + tok];
            u32 sB = scT[(size_t)(d0 + 1) * N_TOK + T0 + tok];
            u32 sC = scT[(size_t)(d0 + 2) * N_TOK + T0 + tok];
            u32 sD = scT[(size_t)(d0 + 3) * N_TOK + T0 + tok];
            ks_bf[d0 + 0][tok] = f2bf(e0 * bf_hi(sA) - e1 * bf_lo(sA));
            ks_bf[d0 + 1][tok] = f2bf(e1 * bf_hi(sB) + e0 * bf_lo(sB));
            ks_bf[d0 + 2][tok] = f2bf(e2 * bf_hi(sC) - e3 * bf_lo(sC));
            ks_bf[d0 + 3][tok] = f2bf(e3 * bf_hi(sD) + e2 * bf_lo(sD));
        }
#pragma unroll
    for (int i = 2; i < 4; ++i)
#pragma unroll
        for (int jj = 0; jj < 4; ++jj) {
            int tok = w * 64 + jj * 16 + fr;
#pragma unroll
            for (int r = 0; r < 4; ++r) {
                int vrow = (i - 2) * 16 + kg * 4 + r;
                float vv_ = acc[i][jj][r] + bv[(i - 2) * 4 + r];
                vspart[(i - 2) * 4 + r] += vv_;
                v_bf[vrow][tok] = f2bf(vv_);
            }
        }
#pragma unroll
    for (int m = 1; m < 16; m <<= 1) {
#pragma unroll
        for (int q = 0; q < 8; ++q) {
            kspart[q] += __shfl_xor(kspart[q], m);
            vspart[q] += __shfl_xor(vspart[q], m);
        }
    }
    if (fr == 0) {
#pragma unroll
        for (int q = 0; q < 8; ++q) {
            int row = (q >> 2) * 16 + kg * 4 + (q & 3);
            redk[w * 32 + row] = kspart[q];
            redv[w * 32 + row] = vspart[q];
        }
    }
    __syncthreads();

    // ---- MFMA outer product over 256 tokens; wave w -> tokens w*64..+63 ----
    f32x4 a2[2][2] = {};
#pragma unroll
    for (int kc = 0; kc < 2; ++kc) {
        int kcol = w * 64 + kc * 32 + kg * 8;
        bf16x8 af[2], bfv[2];
#pragma unroll
        for (int i = 0; i < 2; ++i) {
            af[i]  = *(const bf16x8*)&ks_bf[i * 16 + fr][kcol];
            bfv[i] = *(const bf16x8*)&v_bf[i * 16 + fr][kcol];
        }
#pragma unroll
        for (int i = 0; i < 2; ++i)
#pragma unroll
            for (int jj = 0; jj < 2; ++jj)
                a2[i][jj] = __builtin_amdgcn_mfma_f32_16x16x32_bf16(af[i], bfv[jj], a2[i][jj], 0, 0, 0);
    }

    // ---- cooperative v -> global (for lepe) ----
    {
        int row = t >> 3, tg = t & 7;
        u16* vg = v_glob + ((size_t)(b * C_DIM + n * HD + row)) * N_TOK + T0 + tg * 32;
#pragma unroll
        for (int q = 0; q < 4; ++q)
            *(uint4*)(vg + q * 8) = *(const uint4*)&v_bf[row][tg * 32 + q * 8];
    }
    if (t < 32) {
        float s = redk[t] + redk[32 + t] + redk[64 + t] + redk[96 + t];
        float sv = redv[t] + redv[32 + t] + redv[64 + t] + redv[96 + t];
        part_ks[((size_t)bn * 16 + chunk) * 32 + t] = s;
        part_vs[((size_t)bn * 16 + chunk) * 32 + t] = sv;
    }

#pragma unroll
    for (int i = 0; i < 2; ++i)
#pragma unroll
        for (int jj = 0; jj < 2; ++jj)
#pragma unroll
            for (int r = 0; r < 4; ++r) {
                int row = i * 16 + kg * 4 + r;
                int col = jj * 16 + fr;
                red[w * 1024 + row * 32 + col] = a2[i][jj][r];
            }
    __syncthreads();
    float* pkv = part_kv + ((size_t)bn * 16 + chunk) * 1024;
#pragma unroll
    for (int i = 0; i < 4; ++i) {
        int el = i * 256 + t;
        pkv[el] = red[el] + red[1024 + el] + red[2048 + el] + red[3072 + el];
    }
}

// ---------------- kv_final (blocks 0..63) + lepe (blocks 64..2111) ----------------
__global__ __launch_bounds__(256) void kvfinal_lepe(const float* __restrict__ part_kv, const float* __restrict__ part_ks,
                                                    const float* __restrict__ part_vs, const u16* __restrict__ v_glob,
                                                    const float* __restrict__ wl, const float* __restrict__ bl,
                                                    u16* __restrict__ kvT_bf, float* __restrict__ kmean,
                                                    float* __restrict__ vmean, u16* __restrict__ lepe) {
    __shared__ float wc5[25];
    int bx = blockIdx.x;
    int t = threadIdx.x;
    if (bx < 64) {
        int bn = bx;
        const float* p = part_kv + (size_t)bn * 16 * 1024;
        const float s2c = SCALE_F / (float)N_TOK;
#pragma unroll
        for (int i = 0; i < 4; ++i) {
            int sl = t + i * 256;
            float s = 0;
#pragma unroll
            for (int c = 0; c < 16; ++c) s += p[(size_t)c * 1024 + sl];
            float val = s * s2c;
            int d = sl >> 5, e = sl & 31;
            kvT_bf[(size_t)bn * 1024 + e * 32 + d] = f2bf(val);
        }
        if (t < 32) {
            float s = 0, sv = 0;
            for (int c = 0; c < 16; ++c) {
                s  += part_ks[((size_t)bn * 16 + c) * 32 + t];
                sv += part_vs[((size_t)bn * 16 + c) * 32 + t];
            }
            kmean[bn * 32 + t] = s * (1.f / (float)N_TOK);
            vmean[bn * 32 + t] = sv * (1.f / (float)N_TOK);
        }
        return;
    }
    int i2 = bx - 64;
    int c = i2 & 255, b = i2 >> 8;
    const u16* src = v_glob + ((size_t)(b * C_DIM + c)) * N_TOK;
    u16* dst = lepe + ((size_t)b * C_DIM + c) * N_TOK;
    if (t < 25) wc5[t] = wl[c * 25 + t];
    __syncthreads();

    int h = t >> 2, w0 = (t & 3) * 16;
    float bb = bl[c];
    float o16[16];
#pragma unroll
    for (int i = 0; i < 16; ++i) o16[i] = bb;

#pragma unroll
    for (int dh = 0; dh < 5; ++dh) {
        int gr = h + dh - 2;
        bool rowok = (gr >= 0) && (gr < 64);
        const u16* rp = src + (size_t)(rowok ? gr : 0) * 64 + w0 - 8;
        bf16x8 L0 = ((const bf16x8*)rp)[0];
        bf16x8 L1 = ((const bf16x8*)rp)[1];
        bf16x8 L2 = ((const bf16x8*)rp)[2];
        bf16x8 L3 = ((const bf16x8*)rp)[3];
        float rbuf[32];
#pragma unroll
        for (int j = 0; j < 32; ++j) {
            int col = w0 - 8 + j;
            u16 raw = (u16)(j < 8 ? L0[j] : j < 16 ? L1[j - 8] : j < 24 ? L2[j - 16] : L3[j - 24]);
            bool ok = rowok && (col >= 0) && (col < 64);
            rbuf[j] = ok ? b2f(raw) : 0.f;
        }
#pragma unroll
        for (int dw = 0; dw < 5; ++dw) {
            float wv_ = wc5[dh * 5 + dw];
#pragma unroll
            for (int ow = 0; ow < 16; ++ow)
                o16[ow] += rbuf[6 + dw + ow] * wv_;
        }
    }

    uint4 u0, u1;
    u0.x = (u32)f2bf(o16[0]) | ((u32)f2bf(o16[1]) << 16);
    u0.y = (u32)f2bf(o16[2]) | ((u32)f2bf(o16[3]) << 16);
    u0.z = (u32)f2bf(o16[4]) | ((u32)f2bf(o16[5]) << 16);
    u0.w = (u32)f2bf(o16[6]) | ((u32)f2bf(o16[7]) << 16);
    u1.x = (u32)f2bf(o16[8]) | ((u32)f2bf(o16[9]) << 16);
    u1.y = (u32)f2bf(o16[10]) | ((u32)f2bf(o16[11]) << 16);
    u1.z = (u32)f2bf(o16[12]) | ((u32)f2bf(o16[13]) << 16);
    u1.w = (u32)f2bf(o16[14]) | ((u32)f2bf(o16[15]) << 16);
    *(uint4*)(dst + h * 64 + w0) = u0;
    *(uint4*)(dst + h * 64 + w0 + 8) = u1;
}

// ---------------- attention epilogue: fused q/o GEMM + matvec + finish -> resnT ----------------
__global__ __launch_bounds__(256) void attn_epilogue(const u16* __restrict__ wbf, const float* __restrict__ bq,
                                                     const u16* __restrict__ xT, const u32* __restrict__ scT,
                                                     const u16* __restrict__ kvT_bf, const float* __restrict__ kmean,
                                                     const float* __restrict__ vmean, const u16* __restrict__ lepe,
                                                     u16* __restrict__ resnT) {
    int lt = blockIdx.x, bn = blockIdx.y;
    int b = bn >> 3, n = bn & 7;
    int T0 = lt * 256;
    const u16* lp = lepe + ((size_t)b * C_DIM + n * HD) * N_TOK;
    const u16* Bx = xT + ((size_t)b * N_TOK + T0) * C_DIM;

    __shared__ char smem[64256];
    u16* qA    = (u16*)smem;
    u16* o_lds = (u16*)(smem + 20480);
    u16* Rt    = (u16*)(smem + 40960);
    u16* kvb   = (u16*)(smem + 61440);
    float* kml = (float*)(smem + 64000);
    float* vml = (float*)(smem + 64128);
    u16* Bst = (u16*)smem;
    u16* Ast = (u16*)(smem + 32768);

    int t = threadIdx.x;
    int w = t >> 6, lane = t & 63;
    int fr = lane & 15, kg = lane >> 4;

    if (t < 128) {
        int e = t >> 2, d0 = (t & 3) * 8;
        *(uint4*)(kvb + e * 40 + d0) = *(const uint4*)(kvT_bf + (size_t)bn * 1024 + e * 32 + d0);
    }
    if (t < 32) { kml[t] = kmean[bn * 32 + t]; vml[t] = vmean[bn * 32 + t]; }

    // ---- phase 0: GEMM q,o = W_qo x xT^T ----
    f32x4 acc[4][4] = {};
    for (int k0 = 0; k0 < 256; k0 += 64) {
#pragma unroll
        for (int j = 0; j < 8; ++j) {
            int cc = j * 256 + w * 64 + lane;
            int row = cc >> 3, slot = cc & 7;
            int gslot = slot ^ (row & 7);
            gload16(Bx + (size_t)row * C_DIM + k0 + gslot * 8, Bst + (size_t)(j * 256 + w * 64) * 8);
        }
#pragma unroll
        for (int j = 0; j < 2; ++j) {
            int cc = j * 256 + w * 64 + lane;
            int row = cc >> 3, slot = cc & 7;
            int gslot = slot ^ (row & 7);
            int arow = (row < 32 ? n * HD : 736 + n * HD) + row;
            gload16(wbf + (size_t)arow * C_DIM + k0 + gslot * 8, Ast + (size_t)(j * 256 + w * 64) * 8);
        }
        __syncthreads();
#pragma unroll
        for (int kk = 0; kk < 2; ++kk) {
            bf16x8 af[4], bfr[4];
#pragma unroll
            for (int i = 0; i < 4; ++i) {
                int ra = i * 16 + fr;
                af[i] = *(const bf16x8*)(Ast + (size_t)ra * 64 + (size_t)((kk * 4 + kg) ^ (ra & 7)) * 8);
            }
#pragma unroll
            for (int jj = 0; jj < 4; ++jj) {
                int rb = w * 64 + jj * 16 + fr;
                bfr[jj] = *(const bf16x8*)(Bst + (size_t)rb * 64 + (size_t)((kk * 4 + kg) ^ (rb & 7)) * 8);
            }
#pragma unroll
            for (int i = 0; i < 4; ++i)
#pragma unroll
                for (int jj = 0; jj < 4; ++jj)
                    acc[i][jj] = __builtin_amdgcn_mfma_f32_16x16x32_bf16(af[i], bfr[jj], acc[i][jj], 0, 0, 0);
        }
        __syncthreads();
    }
    int rg = kg * 4;
#pragma unroll
    for (int i = 0; i < 4; ++i)
#pragma unroll
        for (int jj = 0; jj < 4; ++jj) {
            int tok = w * 64 + jj * 16 + fr;
#pragma unroll
            for (int r = 0; r < 4; ++r) {
                int qorow = i * 16 + rg + r;
                int brow = (qorow < 32 ? n * HD : 736 + n * HD) + qorow;
                u16 val = f2bf(acc[i][jj][r] + bq[brow]);
                if (qorow < 32) qA[tok * 40 + qorow] = val;
                else            o_lds[tok * 40 + qorow - 32] = val;
            }
        }
    __syncthreads();

    // ---- phase 1: per-token elu / z / theta -> q' A-tile (in place) ----
    int token = T0 + t;
    float qv[32];
    float z = 0.f;
#pragma unroll
    for (int j = 0; j < 4; ++j) {
        bf16x8 q8 = *(const bf16x8*)(qA + t * 40 + j * 8);
#pragma unroll
        for (int e = 0; e < 8; ++e) {
            float x_ = b2f((u16)q8[e]);
            float e_ = x_ > 0.f ? x_ + 1.f : __expf(x_);
            qv[j * 8 + e] = e_;
            z += e_ * kml[j * 8 + e];
        }
    }
    z *= SCALE_F;
#pragma unroll
    for (int p = 0; p < 16; ++p) {
        u32 sc0 = scT[(size_t)(2 * p) * N_TOK + token];
        u32 sc1 = scT[(size_t)(2 * p + 1) * N_TOK + token];
        float se = bf_lo(sc0), ce = bf_hi(sc0);
        float so = bf_lo(sc1), co = bf_hi(sc1);
        float a = qv[2 * p], bb = qv[2 * p + 1];
        qv[2 * p]     = a * ce - bb * se;
        qv[2 * p + 1] = bb * co + a * so;
    }
    float mult = 1.f + 1.f / (z + 1e-6f);
#pragma unroll
    for (int j4 = 0; j4 < 4; ++j4) {
        uint4 u;
        u.x = (u32)f2bf(qv[8 * j4 + 0]) | ((u32)f2bf(qv[8 * j4 + 1]) << 16);
        u.y = (u32)f2bf(qv[8 * j4 + 2]) | ((u32)f2bf(qv[8 * j4 + 3]) << 16);
        u.z = (u32)f2bf(qv[8 * j4 + 4]) | ((u32)f2bf(qv[8 * j4 + 5]) << 16);
        u.w = (u32)f2bf(qv[8 * j4 + 6]) | ((u32)f2bf(qv[8 * j4 + 7]) << 16);
        *(uint4*)(qA + t * 40 + j4 * 8) = u;
    }
    __syncthreads();

    // ---- phase 2: matvec q' x kv^T ----
    {
        bf16x8 af[4], bfr[2];
#pragma unroll
        for (int i = 0; i < 4; ++i)
            af[i] = *(const bf16x8*)(qA + (size_t)(w * 64 + i * 16 + fr) * 40 + kg * 8);
#pragma unroll
        for (int jj = 0; jj < 2; ++jj)
            bfr[jj] = *(const bf16x8*)(kvb + (jj * 16 + fr) * 40 + kg * 8);

        u16* Rw = Rt + w * 2560;
        f32x4 zero = {0.f, 0.f, 0.f, 0.f};
#pragma unroll
        for (int i = 0; i < 4; ++i)
#pragma unroll
            for (int jj = 0; jj < 2; ++jj) {
                f32x4 a2 = __builtin_amdgcn_mfma_f32_16x16x32_bf16(af[i], bfr[jj], zero, 0, 0, 0);
#pragma unroll
                for (int r = 0; r < 4; ++r)
                    Rw[(i * 16 + kg * 4 + r) * 40 + jj * 16 + fr] = f2bf(a2[r]);
            }
    }
    __syncthreads();

    // ---- phase 3: finish ----
    float res[32], ovv[32];
#pragma unroll
    for (int j = 0; j < 4; ++j) {
        bf16x8 r8 = *(const bf16x8*)(Rt + w * 2560 + lane * 40 + j * 8);
        bf16x8 o8 = *(const bf16x8*)(o_lds + t * 40 + j * 8);
#pragma unroll
        for (int e = 0; e < 8; ++e) {
            res[j * 8 + e] = b2f((u16)r8[e]);
            ovv[j * 8 + e] = b2f((u16)o8[e]);
        }
    }

    u16* dst0 = resnT + ((size_t)b * N_TOK + token) * C_DIM + n * HD;
#pragma unroll
    for (int g = 0; g < 4; ++g) {
        float vv[8];
#pragma unroll
        for (int e2 = 0; e2 < 8; ++e2) {
            int ee = g * 8 + e2;
            float lx = b2f(lp[(size_t)ee * N_TOK + token]);
            float rx = res[ee] * mult - z * vml[ee];
            vv[e2] = (rx + lx) * ovv[ee];
        }
        uint4 u;
        u.x = (u32)f2bf(vv[0]) | ((u32)f2bf(vv[1]) << 16);
        u.y = (u32)f2bf(vv[2]) | ((u32)f2bf(vv[3]) << 16);
        u.z = (u32)f2bf(vv[4]) | ((u32)f2bf(vv[5]) << 16);
        u.w = (u32)f2bf(vv[6]) | ((u32)f2bf(vv[7]) << 16);
        ((uint4*)(dst0 + g * 8))[0] = u;
    }
}

extern "C" void kernel_launch(void* const* d_in, const int* in_sizes, int n_in,
                              void* d_out, int out_size, void* d_ws, size_t ws_size,
                              hipStream_t stream) {
    const float* x      = (const float*)d_in[0];
    const float* sinp   = (const float*)d_in[1];
    const float* cosp   = (const float*)d_in[2];
    const float* w_qkvo = (const float*)d_in[3];
    const float* b_qkvo = (const float*)d_in[4];
    const float* w_lepe = (const float*)d_in[5];
    const float* b_lepe = (const float*)d_in[6];
    const float* w_proj = (const float*)d_in[7];
    const float* b_proj = (const float*)d_in[8];

    char* ws = (char*)d_ws;
    size_t off = 0;
    auto alloc = [&](size_t bytes) { size_t o = off; off = (off + bytes + 255) & ~(size_t)255; return o; };
    u16*   wbf     = (u16*)(ws + alloc((size_t)1024 * 256 * 2));
    u16*   wpbf    = (u16*)(ws + alloc((size_t)256 * 256 * 2));
    u16*   xT      = (u16*)(ws + alloc((size_t)8 * 4096 * 256 * 2));
    u16*   v_glob  = (u16*)(ws + alloc((size_t)8 * 256 * 4096 * 2));
    u16*   lepe    = (u16*)(ws + alloc((size_t)8 * 256 * 4096 * 2));
    u16*   resnT   = (u16*)(ws + alloc((size_t)8 * 4096 * 256 * 2));
    float* part_kv = (float*)(ws + alloc((size_t)64 * 16 * 1024 * 4));
    float* part_ks = (float*)(ws + alloc((size_t)64 * 16 * 32 * 4));
    float* part_vs = (float*)(ws + alloc((size_t)64 * 16 * 32 * 4));
    u16*   kvT_bf  = (u16*)(ws + alloc((size_t)64 * 1024 * 2));
    float* kmean   = (float*)(ws + alloc((size_t)64 * 32 * 4));
    float* vmean   = (float*)(ws + alloc((size_t)64 * 32 * 4));
    u32*   scT     = (u32*)(ws + alloc((size_t)32 * 4096 * 4));
    if (off > ws_size) return;  // insufficient workspace -> loud validation failure

    stage1<<<dim3(3136), dim3(256), 0, stream>>>(x, w_qkvo, w_proj, sinp, cosp, xT, wbf, wpbf, scT);
    stage2_kv<<<dim3(1024), dim3(256), 0, stream>>>(wbf, b_qkvo, xT, scT, v_glob, part_kv, part_ks, part_vs);
    kvfinal_lepe<<<dim3(2112), dim3(256), 0, stream>>>(part_kv, part_ks, part_vs, v_glob, w_lepe, b_lepe,
                                                       kvT_bf, kmean, vmean, lepe);
    attn_epilogue<<<dim3(16, 64), dim3(256), 0, stream>>>(wbf, b_qkvo, xT, scT, kvT_bf, kmean, vmean, lepe, resnT);
    gemm_proj<<<dim3(32, 2, 8), dim3(256), 0, stream>>>(wpbf, resnT, b_proj, (float*)d_out, 256, 4096, 256);
}